// Round 1
// baseline (4921.980 us; speedup 1.0000x reference)
//
#include <hip/hip_runtime.h>
#include <hip/hip_bf16.h>

#define EPS_BN 1e-5f
constexpr int BB = 16, NN = 2048, SS1 = 512, SS2 = 256, KNb = 32;

// ---------------------------------------------------------------- transpose
__global__ void k_transpose(const float* __restrict__ x, float* __restrict__ xyz) {
  int idx = blockIdx.x * blockDim.x + threadIdx.x;
  int total = BB * NN * 3;
  if (idx >= total) return;
  int c = idx % 3; int n = (idx / 3) % NN; int b = idx / (3 * NN);
  xyz[idx] = x[((size_t)b * 3 + c) * NN + n];
}

// ---------------------------------------------------------------- embedding
__global__ void k_emb1(const float* __restrict__ xyz, const float* __restrict__ w,
                       float* __restrict__ out) {
  int idx = blockIdx.x * blockDim.x + threadIdx.x;
  if (idx >= BB * NN * 64) return;
  int o = idx & 63; int pt = idx >> 6;
  const float* p = xyz + (size_t)pt * 3;
  const float* wr = w + o * 3;
  out[idx] = p[0] * wr[0] + p[1] * wr[1] + p[2] * wr[2];
}

__global__ void k_emb2(const float* __restrict__ fin, const float* __restrict__ w,
                       float* __restrict__ out) {
  int idx = blockIdx.x * blockDim.x + threadIdx.x;
  if (idx >= BB * NN * 64) return;
  int o = idx & 63; int pt = idx >> 6;
  const float* f = fin + (size_t)pt * 64;
  const float* wr = w + o * 64;
  float acc = 0.f;
#pragma unroll
  for (int c = 0; c < 64; c++) acc += f[c] * wr[c];
  out[idx] = acc;
}

// per-channel BN stats (direct, one block per channel)
template <int O>
__global__ void k_stats_direct(const float* __restrict__ data, int rows,
                               const float* __restrict__ gamma, const float* __restrict__ beta,
                               float* __restrict__ scale, float* __restrict__ shift) {
  int o = blockIdx.x; int t = threadIdx.x;
  double s = 0.0, s2 = 0.0;
  for (int r = t; r < rows; r += 256) {
    float v = data[(size_t)r * O + o];
    s += v; s2 += (double)v * (double)v;
  }
  __shared__ double ls[256], ls2[256];
  ls[t] = s; ls2[t] = s2; __syncthreads();
  for (int off = 128; off > 0; off >>= 1) {
    if (t < off) { ls[t] += ls[t + off]; ls2[t] += ls2[t + off]; }
    __syncthreads();
  }
  if (t == 0) {
    double mean = ls[0] / rows;
    double var = ls2[0] / rows - mean * mean;
    float sc = gamma[o] * rsqrtf((float)var + EPS_BN);
    scale[o] = sc; shift[o] = beta[o] - (float)mean * sc;
  }
}

__global__ void k_normrelu(float* __restrict__ data, const float* __restrict__ scale,
                           const float* __restrict__ shift, int total, int O) {
  int idx = blockIdx.x * blockDim.x + threadIdx.x;
  if (idx >= total) return;
  int o = idx % O;
  data[idx] = fmaxf(data[idx] * scale[o] + shift[o], 0.f);
}

// ---------------------------------------------------------------- FPS (one block per batch)
__global__ void k_fps(const float* __restrict__ xyz, int N, int S,
                      int* __restrict__ fpsidx, float* __restrict__ newxyz) {
  int b = blockIdx.x; int t = threadIdx.x;
  __shared__ float px[2048], py[2048], pz[2048], dist[2048];
  __shared__ float rv[4]; __shared__ int ri[4]; __shared__ int sfar;
  for (int i = t; i < N; i += 256) {
    size_t base = ((size_t)b * N + i) * 3;
    px[i] = xyz[base]; py[i] = xyz[base + 1]; pz[i] = xyz[base + 2];
    dist[i] = 1e10f;
  }
  __syncthreads();
  int far = 0;
  for (int it = 0; it < S; it++) {
    if (t == 0) {
      fpsidx[b * S + it] = far;
      size_t ob = ((size_t)b * S + it) * 3;
      newxyz[ob] = px[far]; newxyz[ob + 1] = py[far]; newxyz[ob + 2] = pz[far];
    }
    float fx = px[far], fy = py[far], fz = pz[far];
    float bv = -1.f; int bi = 0;
    for (int i = t; i < N; i += 256) {
      float dx = px[i] - fx, dy = py[i] - fy, dz = pz[i] - fz;
      float d = dx * dx + dy * dy + dz * dz;
      float od = dist[i];
      float nd = d < od ? d : od;
      dist[i] = nd;
      if (nd > bv) { bv = nd; bi = i; }
    }
#pragma unroll
    for (int off = 32; off > 0; off >>= 1) {
      float ov = __shfl_down(bv, off); int oi = __shfl_down(bi, off);
      if (ov > bv || (ov == bv && oi < bi)) { bv = ov; bi = oi; }
    }
    int wid = t >> 6, lane = t & 63;
    if (lane == 0) { rv[wid] = bv; ri[wid] = bi; }
    __syncthreads();
    if (t == 0) {
      float bbv = rv[0]; int bbi = ri[0];
      for (int w = 1; w < 4; w++) {
        if (rv[w] > bbv || (rv[w] == bbv && ri[w] < bbi)) { bbv = rv[w]; bbi = ri[w]; }
      }
      sfar = bbi;
    }
    __syncthreads();
    far = sfar;
  }
}

// ---------------------------------------------------------------- KNN (one block per center)
__global__ void k_knn(const float* __restrict__ pts, const float* __restrict__ ctr,
                      int N, int S, int* __restrict__ knn) {
  int blk = blockIdx.x; int b = blk / S; int si = blk % S; int t = threadIdx.x;
  __shared__ float d2[2048];
  __shared__ float rv[4]; __shared__ int ri[4];
  size_t cb = ((size_t)b * S + si) * 3;
  float cx = ctr[cb], cy = ctr[cb + 1], cz = ctr[cb + 2];
  float cn = cx * cx + cy * cy + cz * cz;
  for (int i = t; i < N; i += 256) {
    size_t pb = ((size_t)b * N + i) * 3;
    float xx = pts[pb], yy = pts[pb + 1], zz = pts[pb + 2];
    d2[i] = cn - 2.f * (cx * xx + cy * yy + cz * zz) + (xx * xx + yy * yy + zz * zz);
  }
  __syncthreads();
  for (int kk = 0; kk < KNb; kk++) {
    float bv = 3.4e38f; int bi = 0;
    for (int i = t; i < N; i += 256) {
      float v = d2[i];
      if (v < bv) { bv = v; bi = i; }
    }
#pragma unroll
    for (int off = 32; off > 0; off >>= 1) {
      float ov = __shfl_down(bv, off); int oi = __shfl_down(bi, off);
      if (ov < bv || (ov == bv && oi < bi)) { bv = ov; bi = oi; }
    }
    int wid = t >> 6, lane = t & 63;
    if (lane == 0) { rv[wid] = bv; ri[wid] = bi; }
    __syncthreads();
    if (t == 0) {
      float bbv = rv[0]; int bbi = ri[0];
      for (int w = 1; w < 4; w++) {
        if (rv[w] < bbv || (rv[w] == bbv && ri[w] < bbi)) { bbv = rv[w]; bbi = ri[w]; }
      }
      knn[(size_t)blk * KNb + kk] = bbi;
      d2[bbi] = 3.4e38f;
    }
    __syncthreads();
  }
}

// ---------------------------------------------------------------- GEMM1: agg = [g-cf, cf] @ w1^T + cb1
template <int DF, int O, int BLK>
__global__ __launch_bounds__(BLK) void k_gemm1(
    const float* __restrict__ feat, int N, const int* __restrict__ fpsidx,
    const int* __restrict__ knn, int S,
    const float* __restrict__ w1, const float* __restrict__ cb1,
    __hip_bfloat16* __restrict__ H, double* __restrict__ rsum, double* __restrict__ rsq) {
  int blk = blockIdx.x; int b = blk / S; int t = threadIdx.x;
  __shared__ float cf[DF];
  __shared__ float rel[DF][KNb + 1];
  __shared__ int nbr[KNb];
  if (t < KNb) nbr[t] = knn[(size_t)blk * KNb + t];
  int center = fpsidx[blk];
  for (int c = t; c < DF; c += BLK) cf[c] = feat[((size_t)b * N + center) * DF + c];
  __syncthreads();
  for (int i = t; i < KNb * DF; i += BLK) {
    int kk = i / DF, c = i - kk * DF;
    rel[c][kk] = feat[((size_t)b * N + nbr[kk]) * DF + c] - cf[c];
  }
  __syncthreads();
  constexpr int CPT = O / BLK;
  for (int cc = 0; cc < CPT; cc++) {
    int o = t + cc * BLK;
    const float* wr = w1 + (size_t)o * (2 * DF);
    float t2 = cb1[o];
    for (int c = 0; c < DF; c++) t2 += cf[c] * wr[DF + c];
    float acc[KNb];
#pragma unroll
    for (int kk = 0; kk < KNb; kk++) acc[kk] = t2;
    for (int c = 0; c < DF; c++) {
      float wv = wr[c];
#pragma unroll
      for (int kk = 0; kk < KNb; kk++) acc[kk] += rel[c][kk] * wv;
    }
    double lsum = 0, lsq = 0;
    size_t base = (size_t)blk * KNb * O + o;
    for (int kk = 0; kk < KNb; kk++) {
      float v = acc[kk];
      H[base + (size_t)kk * O] = __float2bfloat16(v);
      lsum += v; lsq += (double)v * (double)v;
    }
    int rep = blk & 63;
    atomicAdd(&rsum[(size_t)rep * O + o], lsum);
    atomicAdd(&rsq[(size_t)rep * O + o], lsq);
  }
}

// ---------------------------------------------------------------- GEMM2: bn_relu(H) @ w2^T + cb2, max/min over k
template <int DI, int O, int BLK>
__global__ __launch_bounds__(BLK) void k_gemm2(
    const __hip_bfloat16* __restrict__ H,
    const float* __restrict__ scale1, const float* __restrict__ shift1,
    const float* __restrict__ w2, const float* __restrict__ cb2,
    float* __restrict__ maxb, float* __restrict__ minb,
    double* __restrict__ rsum, double* __restrict__ rsq) {
  constexpr int CH = (DI > 256) ? 256 : DI;
  int blk = blockIdx.x; int t = threadIdx.x;
  __shared__ float h[CH][KNb + 1];
  constexpr int CPT = O / BLK;
  float acc[CPT][KNb];
#pragma unroll
  for (int cc = 0; cc < CPT; cc++) {
    float bias = cb2[t + cc * BLK];
#pragma unroll
    for (int kk = 0; kk < KNb; kk++) acc[cc][kk] = bias;
  }
  for (int c0 = 0; c0 < DI; c0 += CH) {
    __syncthreads();
    for (int i = t; i < KNb * CH; i += BLK) {
      int kk = i / CH, c = i - kk * CH;
      float v = __bfloat162float(H[((size_t)blk * KNb + kk) * DI + c0 + c]);
      v = v * scale1[c0 + c] + shift1[c0 + c];
      h[c][kk] = fmaxf(v, 0.f);
    }
    __syncthreads();
#pragma unroll
    for (int cc = 0; cc < CPT; cc++) {
      int o = t + cc * BLK;
      const float* wr = w2 + (size_t)o * DI + c0;
      for (int c = 0; c < CH; c++) {
        float wv = wr[c];
#pragma unroll
        for (int kk = 0; kk < KNb; kk++) acc[cc][kk] += h[c][kk] * wv;
      }
    }
  }
#pragma unroll
  for (int cc = 0; cc < CPT; cc++) {
    int o = t + cc * BLK;
    float mx = -3.4e38f, mn = 3.4e38f; double lsum = 0, lsq = 0;
#pragma unroll
    for (int kk = 0; kk < KNb; kk++) {
      float v = acc[cc][kk];
      mx = fmaxf(mx, v); mn = fminf(mn, v);
      lsum += v; lsq += (double)v * (double)v;
    }
    maxb[(size_t)blk * O + o] = mx; minb[(size_t)blk * O + o] = mn;
    int rep = blk & 63;
    atomicAdd(&rsum[(size_t)rep * O + o], lsum);
    atomicAdd(&rsq[(size_t)rep * O + o], lsq);
  }
}

// ---------------------------------------------------------------- finalize BN stats from replicated sums
__global__ void k_finalize(const double* __restrict__ rsum, const double* __restrict__ rsq,
                           int O, int rows,
                           const float* __restrict__ gamma, const float* __restrict__ beta,
                           float* __restrict__ scale, float* __restrict__ shift) {
  int o = blockIdx.x * blockDim.x + threadIdx.x;
  if (o >= O) return;
  double s = 0, s2 = 0;
  for (int r = 0; r < 64; r++) { s += rsum[(size_t)r * O + o]; s2 += rsq[(size_t)r * O + o]; }
  double rowsd = (double)rows;
  double mean = s / rowsd;
  double var = s2 / rowsd - mean * mean;
  float sc = gamma[o] * rsqrtf((float)var + EPS_BN);
  scale[o] = sc; shift[o] = beta[o] - (float)mean * sc;
}

// ---------------------------------------------------------------- epilogues
__global__ void k_final_feat(const float* __restrict__ maxb, const float* __restrict__ minb,
                             const float* __restrict__ scale, const float* __restrict__ shift,
                             float* __restrict__ out, int total, int O) {
  int idx = blockIdx.x * blockDim.x + threadIdx.x;
  if (idx >= total) return;
  int o = idx % O; float sc = scale[o];
  float sel = sc > 0.f ? maxb[idx] : minb[idx];
  out[idx] = fmaxf(sel * sc + shift[o], 0.f);
}

__global__ void k_final_out(const float* __restrict__ maxb, const float* __restrict__ minb,
                            const float* __restrict__ scale, const float* __restrict__ shift,
                            float* __restrict__ out) {
  int idx = blockIdx.x * blockDim.x + threadIdx.x;
  int total = BB * SS2 * 512;
  if (idx >= total) return;
  int o = idx % 512; int si = (idx / 512) % SS2; int b = idx / (512 * SS2);
  float sc = scale[o];
  float sel = sc > 0.f ? maxb[idx] : minb[idx];
  out[((size_t)b * 512 + o) * SS2 + si] = fmaxf(sel * sc + shift[o], 0.f);
}

// ---------------------------------------------------------------- host
extern "C" void kernel_launch(void* const* d_in, const int* in_sizes, int n_in,
                              void* d_out, int out_size, void* d_ws, size_t ws_size,
                              hipStream_t stream) {
  const float* x       = (const float*)d_in[0];
  const float* emb_w1  = (const float*)d_in[1];
  const float* emb_g1  = (const float*)d_in[2];
  const float* emb_b1  = (const float*)d_in[3];
  const float* emb_w2  = (const float*)d_in[4];
  const float* emb_g2  = (const float*)d_in[5];
  const float* emb_b2  = (const float*)d_in[6];
  const float* sg1_w1  = (const float*)d_in[7];
  const float* sg1_cb1 = (const float*)d_in[8];
  const float* sg1_g1  = (const float*)d_in[9];
  const float* sg1_b1  = (const float*)d_in[10];
  const float* sg1_w2  = (const float*)d_in[11];
  const float* sg1_cb2 = (const float*)d_in[12];
  const float* sg1_g2  = (const float*)d_in[13];
  const float* sg1_b2  = (const float*)d_in[14];
  const float* sg2_w1  = (const float*)d_in[15];
  const float* sg2_cb1 = (const float*)d_in[16];
  const float* sg2_g1  = (const float*)d_in[17];
  const float* sg2_b1  = (const float*)d_in[18];
  const float* sg2_w2  = (const float*)d_in[19];
  const float* sg2_cb2 = (const float*)d_in[20];
  const float* sg2_g2  = (const float*)d_in[21];
  const float* sg2_b2  = (const float*)d_in[22];

  char* ws = (char*)d_ws;
  size_t off = 0;
  auto alloc = [&](size_t bytes) -> size_t {
    size_t cur = off; off += (bytes + 255) & ~(size_t)255; return cur;
  };
  float* xyz  = (float*)(ws + alloc((size_t)BB * NN * 3 * 4));
  float* fA   = (float*)(ws + alloc((size_t)BB * NN * 64 * 4));
  float* fB   = (float*)(ws + alloc((size_t)BB * NN * 64 * 4));
  float* f1   = (float*)(ws + alloc((size_t)BB * SS1 * 128 * 4));
  float* nx1  = (float*)(ws + alloc((size_t)BB * SS1 * 3 * 4));
  float* nx2  = (float*)(ws + alloc((size_t)BB * SS2 * 3 * 4));
  int* fps1   = (int*)(ws + alloc((size_t)BB * SS1 * 4));
  int* fps2   = (int*)(ws + alloc((size_t)BB * SS2 * 4));
  int* knn1   = (int*)(ws + alloc((size_t)BB * SS1 * KNb * 4));
  int* knn2   = (int*)(ws + alloc((size_t)BB * SS2 * KNb * 4));
  float* maxb = (float*)(ws + alloc((size_t)BB * SS2 * 512 * 4));
  float* minb = (float*)(ws + alloc((size_t)BB * SS2 * 512 * 4));
  float* scbuf = (float*)(ws + alloc((size_t)12 * 512 * 4));
  float* sc_e1 = scbuf + 0 * 512, *sh_e1 = scbuf + 1 * 512;
  float* sc_e2 = scbuf + 2 * 512, *sh_e2 = scbuf + 3 * 512;
  float* sc11 = scbuf + 4 * 512, *sh11 = scbuf + 5 * 512;
  float* sc12 = scbuf + 6 * 512, *sh12 = scbuf + 7 * 512;
  float* sc21 = scbuf + 8 * 512, *sh21 = scbuf + 9 * 512;
  float* sc22 = scbuf + 10 * 512, *sh22 = scbuf + 11 * 512;
  size_t statsz = (size_t)8 * 64 * 512 * 8;
  char* statz = ws + alloc(statsz);
  double* st = (double*)statz;
  double* rsA = st + 0 * 64 * 512, *rqA = st + 1 * 64 * 512;
  double* rsB = st + 2 * 64 * 512, *rqB = st + 3 * 64 * 512;
  double* rsC = st + 4 * 64 * 512, *rqC = st + 5 * 64 * 512;
  double* rsD = st + 6 * 64 * 512, *rqD = st + 7 * 64 * 512;
  __hip_bfloat16* H = (__hip_bfloat16*)(ws + alloc((size_t)BB * SS2 * KNb * 512 * 2));

  hipMemsetAsync(statz, 0, statsz, stream);

  const int thr = 256;
  k_transpose<<<(BB * NN * 3 + thr - 1) / thr, thr, 0, stream>>>(x, xyz);
  k_emb1<<<(BB * NN * 64 + thr - 1) / thr, thr, 0, stream>>>(xyz, emb_w1, fA);
  k_stats_direct<64><<<64, 256, 0, stream>>>(fA, BB * NN, emb_g1, emb_b1, sc_e1, sh_e1);
  k_normrelu<<<(BB * NN * 64 + thr - 1) / thr, thr, 0, stream>>>(fA, sc_e1, sh_e1, BB * NN * 64, 64);
  k_emb2<<<(BB * NN * 64 + thr - 1) / thr, thr, 0, stream>>>(fA, emb_w2, fB);
  k_stats_direct<64><<<64, 256, 0, stream>>>(fB, BB * NN, emb_g2, emb_b2, sc_e2, sh_e2);
  k_normrelu<<<(BB * NN * 64 + thr - 1) / thr, thr, 0, stream>>>(fB, sc_e2, sh_e2, BB * NN * 64, 64);

  k_fps<<<BB, 256, 0, stream>>>(xyz, NN, SS1, fps1, nx1);
  k_knn<<<BB * SS1, 256, 0, stream>>>(xyz, nx1, NN, SS1, knn1);

  k_gemm1<64, 128, 128><<<BB * SS1, 128, 0, stream>>>(fB, NN, fps1, knn1, SS1,
                                                      sg1_w1, sg1_cb1, H, rsA, rqA);
  k_finalize<<<1, 128, 0, stream>>>(rsA, rqA, 128, BB * SS1 * KNb, sg1_g1, sg1_b1, sc11, sh11);
  k_gemm2<128, 128, 128><<<BB * SS1, 128, 0, stream>>>(H, sc11, sh11, sg1_w2, sg1_cb2,
                                                       maxb, minb, rsB, rqB);
  k_finalize<<<1, 128, 0, stream>>>(rsB, rqB, 128, BB * SS1 * KNb, sg1_g2, sg1_b2, sc12, sh12);
  k_final_feat<<<(BB * SS1 * 128 + thr - 1) / thr, thr, 0, stream>>>(maxb, minb, sc12, sh12,
                                                                     f1, BB * SS1 * 128, 128);

  k_fps<<<BB, 256, 0, stream>>>(nx1, SS1, SS2, fps2, nx2);
  k_knn<<<BB * SS2, 256, 0, stream>>>(nx1, nx2, SS1, SS2, knn2);

  k_gemm1<128, 512, 256><<<BB * SS2, 256, 0, stream>>>(f1, SS1, fps2, knn2, SS2,
                                                       sg2_w1, sg2_cb1, H, rsC, rqC);
  k_finalize<<<4, 128, 0, stream>>>(rsC, rqC, 512, BB * SS2 * KNb, sg2_g1, sg2_b1, sc21, sh21);
  k_gemm2<512, 512, 256><<<BB * SS2, 256, 0, stream>>>(H, sc21, sh21, sg2_w2, sg2_cb2,
                                                       maxb, minb, rsD, rqD);
  k_finalize<<<4, 128, 0, stream>>>(rsD, rqD, 512, BB * SS2 * KNb, sg2_g2, sg2_b2, sc22, sh22);
  k_final_out<<<(BB * SS2 * 512 + thr - 1) / thr, thr, 0, stream>>>(maxb, minb, sc22, sh22,
                                                                    (float*)d_out);
}

// Round 2
// 2329.115 us; speedup vs baseline: 2.1132x; 2.1132x over previous
//
#include <hip/hip_runtime.h>
#include <hip/hip_bf16.h>

#define EPS_BN 1e-5f
constexpr int BB = 16, NN = 2048, SS1 = 512, SS2 = 256, KNb = 32;

typedef short bf16x8 __attribute__((ext_vector_type(8)));
typedef float f32x4 __attribute__((ext_vector_type(4)));

__device__ inline float bflo(unsigned u) { return __uint_as_float(u << 16); }
__device__ inline float bfhi(unsigned u) { return __uint_as_float(u & 0xffff0000u); }
__device__ inline unsigned short f2bf_bits(float v) {
  __hip_bfloat16 h = __float2bfloat16(v);
  return *reinterpret_cast<unsigned short*>(&h);
}

// ---------------------------------------------------------------- transpose
__global__ void k_transpose(const float* __restrict__ x, float* __restrict__ xyz) {
  int idx = blockIdx.x * blockDim.x + threadIdx.x;
  if (idx >= BB * NN * 3) return;
  int c = idx % 3; int n = (idx / 3) % NN; int b = idx / (3 * NN);
  xyz[idx] = x[((size_t)b * 3 + c) * NN + n];
}

// ---------------------------------------------------------------- embedding (cheap, keep scalar)
__global__ void k_emb1(const float* __restrict__ xyz, const float* __restrict__ w,
                       float* __restrict__ out) {
  int idx = blockIdx.x * blockDim.x + threadIdx.x;
  if (idx >= BB * NN * 64) return;
  int o = idx & 63; int pt = idx >> 6;
  const float* p = xyz + (size_t)pt * 3;
  const float* wr = w + o * 3;
  out[idx] = p[0] * wr[0] + p[1] * wr[1] + p[2] * wr[2];
}

__global__ void k_emb2(const float* __restrict__ fin, const float* __restrict__ w,
                       float* __restrict__ out) {
  int idx = blockIdx.x * blockDim.x + threadIdx.x;
  if (idx >= BB * NN * 64) return;
  int o = idx & 63; int pt = idx >> 6;
  const float* f = fin + (size_t)pt * 64;
  const float* wr = w + o * 64;
  float acc = 0.f;
#pragma unroll
  for (int c = 0; c < 64; c++) acc += f[c] * wr[c];
  out[idx] = acc;
}

template <int O>
__global__ void k_stats_direct(const float* __restrict__ data, int rows,
                               const float* __restrict__ gamma, const float* __restrict__ beta,
                               float* __restrict__ scale, float* __restrict__ shift) {
  int o = blockIdx.x; int t = threadIdx.x;
  double s = 0.0, s2 = 0.0;
  for (int r = t; r < rows; r += 256) {
    float v = data[(size_t)r * O + o];
    s += v; s2 += (double)v * (double)v;
  }
  __shared__ double ls[256], ls2[256];
  ls[t] = s; ls2[t] = s2; __syncthreads();
  for (int off = 128; off > 0; off >>= 1) {
    if (t < off) { ls[t] += ls[t + off]; ls2[t] += ls2[t + off]; }
    __syncthreads();
  }
  if (t == 0) {
    double mean = ls[0] / rows;
    double var = ls2[0] / rows - mean * mean;
    float sc = gamma[o] * rsqrtf((float)var + EPS_BN);
    scale[o] = sc; shift[o] = beta[o] - (float)mean * sc;
  }
}

__global__ void k_normrelu(float* __restrict__ data, const float* __restrict__ scale,
                           const float* __restrict__ shift, int total, int O) {
  int idx = blockIdx.x * blockDim.x + threadIdx.x;
  if (idx >= total) return;
  int o = idx % O;
  data[idx] = fmaxf(data[idx] * scale[o] + shift[o], 0.f);
}

// ---------------------------------------------------------------- FPS (one block per batch)
__global__ void k_fps(const float* __restrict__ xyz, int N, int S,
                      int* __restrict__ fpsidx, float* __restrict__ newxyz) {
  int b = blockIdx.x; int t = threadIdx.x;
  __shared__ float px[2048], py[2048], pz[2048], dist[2048];
  __shared__ float rv[4]; __shared__ int ri[4]; __shared__ int sfar;
  for (int i = t; i < N; i += 256) {
    size_t base = ((size_t)b * N + i) * 3;
    px[i] = xyz[base]; py[i] = xyz[base + 1]; pz[i] = xyz[base + 2];
    dist[i] = 1e10f;
  }
  __syncthreads();
  int far = 0;
  for (int it = 0; it < S; it++) {
    if (t == 0) {
      fpsidx[b * S + it] = far;
      size_t ob = ((size_t)b * S + it) * 3;
      newxyz[ob] = px[far]; newxyz[ob + 1] = py[far]; newxyz[ob + 2] = pz[far];
    }
    float fx = px[far], fy = py[far], fz = pz[far];
    float bv = -1.f; int bi = 0;
    for (int i = t; i < N; i += 256) {
      float dx = px[i] - fx, dy = py[i] - fy, dz = pz[i] - fz;
      float d = dx * dx + dy * dy + dz * dz;
      float od = dist[i];
      float nd = d < od ? d : od;
      dist[i] = nd;
      if (nd > bv) { bv = nd; bi = i; }
    }
#pragma unroll
    for (int off = 32; off > 0; off >>= 1) {
      float ov = __shfl_down(bv, off); int oi = __shfl_down(bi, off);
      if (ov > bv || (ov == bv && oi < bi)) { bv = ov; bi = oi; }
    }
    int wid = t >> 6, lane = t & 63;
    if (lane == 0) { rv[wid] = bv; ri[wid] = bi; }
    __syncthreads();
    if (t == 0) {
      float bbv = rv[0]; int bbi = ri[0];
      for (int w = 1; w < 4; w++) {
        if (rv[w] > bbv || (rv[w] == bbv && ri[w] < bbi)) { bbv = rv[w]; bbi = ri[w]; }
      }
      sfar = bbi;
    }
    __syncthreads();
    far = sfar;
  }
}

// ---------------------------------------------------------------- KNN (one block per center)
__global__ void k_knn(const float* __restrict__ pts, const float* __restrict__ ctr,
                      int N, int S, int* __restrict__ knn) {
  int blk = blockIdx.x; int b = blk / S; int t = threadIdx.x;
  __shared__ float d2[2048];
  __shared__ float rv[4]; __shared__ int ri[4];
  size_t cb = ((size_t)blk) * 3;
  float cx = ctr[cb], cy = ctr[cb + 1], cz = ctr[cb + 2];
  float cn = cx * cx + cy * cy + cz * cz;
  for (int i = t; i < N; i += 256) {
    size_t pb = ((size_t)b * N + i) * 3;
    float xx = pts[pb], yy = pts[pb + 1], zz = pts[pb + 2];
    d2[i] = cn - 2.f * (cx * xx + cy * yy + cz * zz) + (xx * xx + yy * yy + zz * zz);
  }
  __syncthreads();
  for (int kk = 0; kk < KNb; kk++) {
    float bv = 3.4e38f; int bi = 0;
    for (int i = t; i < N; i += 256) {
      float v = d2[i];
      if (v < bv) { bv = v; bi = i; }
    }
#pragma unroll
    for (int off = 32; off > 0; off >>= 1) {
      float ov = __shfl_down(bv, off); int oi = __shfl_down(bi, off);
      if (ov < bv || (ov == bv && oi < bi)) { bv = ov; bi = oi; }
    }
    int wid = t >> 6, lane = t & 63;
    if (lane == 0) { rv[wid] = bv; ri[wid] = bi; }
    __syncthreads();
    if (t == 0) {
      float bbv = rv[0]; int bbi = ri[0];
      for (int w = 1; w < 4; w++) {
        if (rv[w] < bbv || (rv[w] == bbv && ri[w] < bbi)) { bbv = rv[w]; bbi = ri[w]; }
      }
      knn[(size_t)blk * KNb + kk] = bbi;
      d2[bbi] = 3.4e38f;
    }
    __syncthreads();
  }
}

// ---------------------------------------------------------------- fp32 -> bf16 convert
__global__ void k_f2bf(const float* __restrict__ w, __hip_bfloat16* __restrict__ o, int n) {
  int i = blockIdx.x * blockDim.x + threadIdx.x;
  if (i < n) o[i] = __float2bfloat16(w[i]);
}

// ---------------------------------------------------------------- gather: A = [rel | cf] bf16
template <int D>
__global__ __launch_bounds__(256) void k_gather(const float* __restrict__ feat, int N,
                                                const int* __restrict__ fpsidx,
                                                const int* __restrict__ knn, int S,
                                                __hip_bfloat16* __restrict__ A) {
  int blk = blockIdx.x; int b = blk / S; int t = threadIdx.x;
  __shared__ float cf[D]; __shared__ int nbr[KNb];
  if (t < KNb) nbr[t] = knn[(size_t)blk * KNb + t];
  int center = fpsidx[blk];
  for (int c = t; c < D; c += 256) cf[c] = feat[((size_t)b * N + center) * D + c];
  __syncthreads();
  for (int i = t; i < KNb * D; i += 256) {
    int kk = i / D, c = i - kk * D;
    float v = feat[((size_t)b * N + nbr[kk]) * D + c];
    size_t row = (size_t)blk * KNb + kk;
    A[row * (2 * D) + c] = __float2bfloat16(v - cf[c]);
    A[row * (2 * D) + D + c] = __float2bfloat16(cf[c]);
  }
}

// ---------------------------------------------------------------- MFMA GEMM: C = A[M,K] @ W[N,K]^T + bias
// EPI 0: store bf16 C. EPI 1: per-32-row-group max/min + column sum/sumsq (C not materialized).
template <int K, int EPI>
__global__ __launch_bounds__(256) void k_mgemm(
    const __hip_bfloat16* __restrict__ A, const __hip_bfloat16* __restrict__ W,
    int N, int Mtiles, const float* __restrict__ bias,
    __hip_bfloat16* __restrict__ Hout,
    float* __restrict__ maxb, float* __restrict__ minb,
    double* __restrict__ rsum, double* __restrict__ rsq) {
  constexpr int SP = 40;  // LDS row stride in shorts (padded: 80B = 20 banks -> 2-way max)
  int bm = blockIdx.x % Mtiles; int bn = blockIdx.x / Mtiles;
  int t = threadIdx.x; int w = t >> 6; int lane = t & 63;
  int wm = w & 1, wn = w >> 1; int quad = lane >> 4; int l15 = lane & 15;
  __shared__ short As[128 * SP];
  __shared__ short Ws[128 * SP];
  f32x4 acc[4][4];
  f32x4 zero = {0.f, 0.f, 0.f, 0.f};
#pragma unroll
  for (int i = 0; i < 4; i++)
#pragma unroll
    for (int j = 0; j < 4; j++) acc[i][j] = zero;

  int srow = t >> 2, sseg = t & 3;
  const short* Ag = (const short*)A;
  const short* Wg = (const short*)W;
  size_t arow0 = (size_t)bm * 128;
  size_t wrow0 = (size_t)bn * 128;

  for (int k0 = 0; k0 < K; k0 += 32) {
    __syncthreads();
    uint4 a0 = *(const uint4*)(Ag + (arow0 + srow) * K + k0 + sseg * 8);
    uint4 a1 = *(const uint4*)(Ag + (arow0 + srow + 64) * K + k0 + sseg * 8);
    uint4 b0 = *(const uint4*)(Wg + (wrow0 + srow) * K + k0 + sseg * 8);
    uint4 b1 = *(const uint4*)(Wg + (wrow0 + srow + 64) * K + k0 + sseg * 8);
    *(uint4*)(As + srow * SP + sseg * 8) = a0;
    *(uint4*)(As + (srow + 64) * SP + sseg * 8) = a1;
    *(uint4*)(Ws + srow * SP + sseg * 8) = b0;
    *(uint4*)(Ws + (srow + 64) * SP + sseg * 8) = b1;
    __syncthreads();
    bf16x8 af[4], bfr[4];
#pragma unroll
    for (int i = 0; i < 4; i++)
      af[i] = *(const bf16x8*)(As + (wm * 64 + i * 16 + l15) * SP + quad * 8);
#pragma unroll
    for (int j = 0; j < 4; j++)
      bfr[j] = *(const bf16x8*)(Ws + (wn * 64 + j * 16 + l15) * SP + quad * 8);
#pragma unroll
    for (int i = 0; i < 4; i++)
#pragma unroll
      for (int j = 0; j < 4; j++)
        acc[i][j] = __builtin_amdgcn_mfma_f32_16x16x32_bf16(af[i], bfr[j], acc[i][j], 0, 0, 0);
  }

  if constexpr (EPI == 0) {
#pragma unroll
    for (int i = 0; i < 4; i++)
#pragma unroll
      for (int j = 0; j < 4; j++) {
        int col = bn * 128 + wn * 64 + j * 16 + l15;
        float bs = bias[col];
#pragma unroll
        for (int r = 0; r < 4; r++) {
          int row = bm * 128 + wm * 64 + i * 16 + quad * 4 + r;
          Hout[(size_t)row * N + col] = __float2bfloat16(acc[i][j][r] + bs);
        }
      }
  } else {
    __shared__ float buf[128][33];
    for (int s = 0; s < 4; s++) {
      __syncthreads();
      if (wn == (s >> 1)) {
        int jb = 2 * (s & 1);
#pragma unroll
        for (int jj = 0; jj < 2; jj++) {
          int j = jb + jj;
          int lcol = jj * 16 + l15;
          float bs = bias[bn * 128 + s * 32 + lcol];
#pragma unroll
          for (int i = 0; i < 4; i++)
#pragma unroll
            for (int r = 0; r < 4; r++)
              buf[wm * 64 + i * 16 + quad * 4 + r][lcol] = acc[i][j][r] + bs;
        }
      }
      __syncthreads();
      if (t < 128) {
        int g = t >> 5, c = t & 31;
        float mx = -3.4e38f, mn = 3.4e38f, su = 0.f, sq = 0.f;
#pragma unroll
        for (int r = 0; r < 32; r++) {
          float v = buf[g * 32 + r][c];
          mx = fmaxf(mx, v); mn = fminf(mn, v);
          su += v; sq += v * v;
        }
        int col = bn * 128 + s * 32 + c;
        size_t gidx = (size_t)bm * 4 + g;
        maxb[gidx * N + col] = mx;
        minb[gidx * N + col] = mn;
        int rep = blockIdx.x & 63;
        atomicAdd(&rsum[(size_t)rep * N + col], (double)su);
        atomicAdd(&rsq[(size_t)rep * N + col], (double)sq);
      }
    }
  }
}

// ---------------------------------------------------------------- column stats over bf16 matrix
__global__ __launch_bounds__(256) void k_colstats(const __hip_bfloat16* __restrict__ Hm, int O,
                                                  int iters, double* __restrict__ rsum,
                                                  double* __restrict__ rsq) {
  __shared__ float lsum[512], lsq[512];
  int t = threadIdx.x;
  for (int c = t; c < O; c += 256) { lsum[c] = 0.f; lsq[c] = 0.f; }
  __syncthreads();
  size_t base = (size_t)blockIdx.x * 2048 * iters + t * 8;
  float as[8], aq[8];
#pragma unroll
  for (int j = 0; j < 8; j++) { as[j] = 0.f; aq[j] = 0.f; }
  const unsigned* Hu = (const unsigned*)Hm;
  for (int it = 0; it < iters; it++) {
    uint4 raw = *(const uint4*)(Hu + (base + (size_t)it * 2048) / 2);
    unsigned ws_[4] = {raw.x, raw.y, raw.z, raw.w};
#pragma unroll
    for (int k = 0; k < 4; k++) {
      float v0 = bflo(ws_[k]), v1 = bfhi(ws_[k]);
      as[2 * k] += v0; aq[2 * k] += v0 * v0;
      as[2 * k + 1] += v1; aq[2 * k + 1] += v1 * v1;
    }
  }
  int c0 = (t * 8) & (O - 1);
#pragma unroll
  for (int j = 0; j < 8; j++) {
    atomicAdd(&lsum[c0 + j], as[j]);
    atomicAdd(&lsq[c0 + j], aq[j]);
  }
  __syncthreads();
  int rep = blockIdx.x & 63;
  for (int c = t; c < O; c += 256) {
    atomicAdd(&rsum[(size_t)rep * O + c], (double)lsum[c]);
    atomicAdd(&rsq[(size_t)rep * O + c], (double)lsq[c]);
  }
}

// ---------------------------------------------------------------- in-place BN+ReLU on bf16 matrix
__global__ __launch_bounds__(256) void k_bnrelu(__hip_bfloat16* __restrict__ Hm, int O, int iters,
                                                const float* __restrict__ sc,
                                                const float* __restrict__ sh) {
  int t = threadIdx.x;
  size_t base = (size_t)blockIdx.x * 2048 * iters + t * 8;
  int c0 = (t * 8) & (O - 1);
  float s[8], h[8];
#pragma unroll
  for (int j = 0; j < 8; j++) { s[j] = sc[c0 + j]; h[j] = sh[c0 + j]; }
  unsigned* Hu = (unsigned*)Hm;
  for (int it = 0; it < iters; it++) {
    size_t e = (base + (size_t)it * 2048) / 2;
    uint4 raw = *(uint4*)(Hu + e);
    unsigned ws_[4] = {raw.x, raw.y, raw.z, raw.w};
    unsigned out[4];
#pragma unroll
    for (int k = 0; k < 4; k++) {
      float v0 = fmaxf(bflo(ws_[k]) * s[2 * k] + h[2 * k], 0.f);
      float v1 = fmaxf(bfhi(ws_[k]) * s[2 * k + 1] + h[2 * k + 1], 0.f);
      out[k] = (unsigned)f2bf_bits(v0) | ((unsigned)f2bf_bits(v1) << 16);
    }
    uint4 o4 = {out[0], out[1], out[2], out[3]};
    *(uint4*)(Hu + e) = o4;
  }
}

// ---------------------------------------------------------------- finalize BN stats
__global__ void k_finalize(const double* __restrict__ rsum, const double* __restrict__ rsq,
                           int O, int rows,
                           const float* __restrict__ gamma, const float* __restrict__ beta,
                           float* __restrict__ scale, float* __restrict__ shift) {
  int o = blockIdx.x * blockDim.x + threadIdx.x;
  if (o >= O) return;
  double s = 0, s2 = 0;
  for (int r = 0; r < 64; r++) { s += rsum[(size_t)r * O + o]; s2 += rsq[(size_t)r * O + o]; }
  double mean = s / rows;
  double var = s2 / rows - mean * mean;
  float sc = gamma[o] * rsqrtf((float)var + EPS_BN);
  scale[o] = sc; shift[o] = beta[o] - (float)mean * sc;
}

// ---------------------------------------------------------------- epilogues
__global__ void k_final_feat(const float* __restrict__ maxb, const float* __restrict__ minb,
                             const float* __restrict__ scale, const float* __restrict__ shift,
                             float* __restrict__ out, int total, int O) {
  int idx = blockIdx.x * blockDim.x + threadIdx.x;
  if (idx >= total) return;
  int o = idx % O; float sc = scale[o];
  float sel = sc > 0.f ? maxb[idx] : minb[idx];
  out[idx] = fmaxf(sel * sc + shift[o], 0.f);
}

__global__ void k_final_out(const float* __restrict__ maxb, const float* __restrict__ minb,
                            const float* __restrict__ scale, const float* __restrict__ shift,
                            float* __restrict__ out) {
  int idx = blockIdx.x * blockDim.x + threadIdx.x;
  if (idx >= BB * SS2 * 512) return;
  int o = idx % 512; int si = (idx / 512) % SS2; int b = idx / (512 * SS2);
  float sc = scale[o];
  float sel = sc > 0.f ? maxb[idx] : minb[idx];
  out[((size_t)b * 512 + o) * SS2 + si] = fmaxf(sel * sc + shift[o], 0.f);
}

// ---------------------------------------------------------------- host
extern "C" void kernel_launch(void* const* d_in, const int* in_sizes, int n_in,
                              void* d_out, int out_size, void* d_ws, size_t ws_size,
                              hipStream_t stream) {
  const float* x       = (const float*)d_in[0];
  const float* emb_w1  = (const float*)d_in[1];
  const float* emb_g1  = (const float*)d_in[2];
  const float* emb_b1  = (const float*)d_in[3];
  const float* emb_w2  = (const float*)d_in[4];
  const float* emb_g2  = (const float*)d_in[5];
  const float* emb_b2  = (const float*)d_in[6];
  const float* sg1_w1  = (const float*)d_in[7];
  const float* sg1_cb1 = (const float*)d_in[8];
  const float* sg1_g1  = (const float*)d_in[9];
  const float* sg1_b1  = (const float*)d_in[10];
  const float* sg1_w2  = (const float*)d_in[11];
  const float* sg1_cb2 = (const float*)d_in[12];
  const float* sg1_g2  = (const float*)d_in[13];
  const float* sg1_b2  = (const float*)d_in[14];
  const float* sg2_w1  = (const float*)d_in[15];
  const float* sg2_cb1 = (const float*)d_in[16];
  const float* sg2_g1  = (const float*)d_in[17];
  const float* sg2_b1  = (const float*)d_in[18];
  const float* sg2_w2  = (const float*)d_in[19];
  const float* sg2_cb2 = (const float*)d_in[20];
  const float* sg2_g2  = (const float*)d_in[21];
  const float* sg2_b2  = (const float*)d_in[22];

  char* ws = (char*)d_ws;
  size_t off = 0;
  auto alloc = [&](size_t bytes) -> size_t {
    size_t cur = off; off += (bytes + 255) & ~(size_t)255; return cur;
  };
  float* xyz  = (float*)(ws + alloc((size_t)BB * NN * 3 * 4));
  float* fA   = (float*)(ws + alloc((size_t)BB * NN * 64 * 4));
  float* fB   = (float*)(ws + alloc((size_t)BB * NN * 64 * 4));
  float* f1   = (float*)(ws + alloc((size_t)BB * SS1 * 128 * 4));
  float* nx1  = (float*)(ws + alloc((size_t)BB * SS1 * 3 * 4));
  float* nx2  = (float*)(ws + alloc((size_t)BB * SS2 * 3 * 4));
  int* fps1   = (int*)(ws + alloc((size_t)BB * SS1 * 4));
  int* fps2   = (int*)(ws + alloc((size_t)BB * SS2 * 4));
  int* knn1   = (int*)(ws + alloc((size_t)BB * SS1 * KNb * 4));
  int* knn2   = (int*)(ws + alloc((size_t)BB * SS2 * KNb * 4));
  float* maxb = (float*)(ws + alloc((size_t)BB * SS2 * 512 * 4));
  float* minb = (float*)(ws + alloc((size_t)BB * SS2 * 512 * 4));
  float* scbuf = (float*)(ws + alloc((size_t)12 * 512 * 4));
  float* sc11 = scbuf + 4 * 512, *sh11 = scbuf + 5 * 512;
  float* sc12 = scbuf + 6 * 512, *sh12 = scbuf + 7 * 512;
  float* sc21 = scbuf + 8 * 512, *sh21 = scbuf + 9 * 512;
  float* sc22 = scbuf + 10 * 512, *sh22 = scbuf + 11 * 512;
  float* sc_e1 = scbuf + 0 * 512, *sh_e1 = scbuf + 1 * 512;
  float* sc_e2 = scbuf + 2 * 512, *sh_e2 = scbuf + 3 * 512;
  size_t statsz = (size_t)8 * 64 * 512 * 8;
  char* statz = ws + alloc(statsz);
  double* st = (double*)statz;
  double* rsA = st + 0 * 64 * 512, *rqA = st + 1 * 64 * 512;
  double* rsB = st + 2 * 64 * 512, *rqB = st + 3 * 64 * 512;
  double* rsC = st + 4 * 64 * 512, *rqC = st + 5 * 64 * 512;
  double* rsD = st + 6 * 64 * 512, *rqD = st + 7 * 64 * 512;
  // bf16 weights
  __hip_bfloat16* wb11 = (__hip_bfloat16*)(ws + alloc(128 * 128 * 2));
  __hip_bfloat16* wb12 = (__hip_bfloat16*)(ws + alloc(128 * 128 * 2));
  __hip_bfloat16* wb21 = (__hip_bfloat16*)(ws + alloc(512 * 256 * 2));
  __hip_bfloat16* wb22 = (__hip_bfloat16*)(ws + alloc(512 * 512 * 2));
  // big buffers
  __hip_bfloat16* Abuf = (__hip_bfloat16*)(ws + alloc((size_t)262144 * 128 * 2));  // 64MB
  __hip_bfloat16* Hbuf = (__hip_bfloat16*)(ws + alloc((size_t)131072 * 512 * 2));  // 128MB

  hipMemsetAsync(statz, 0, statsz, stream);

  const int thr = 256;
  k_transpose<<<(BB * NN * 3 + thr - 1) / thr, thr, 0, stream>>>(x, xyz);
  k_emb1<<<(BB * NN * 64 + thr - 1) / thr, thr, 0, stream>>>(xyz, emb_w1, fA);
  k_stats_direct<64><<<64, 256, 0, stream>>>(fA, BB * NN, emb_g1, emb_b1, sc_e1, sh_e1);
  k_normrelu<<<(BB * NN * 64 + thr - 1) / thr, thr, 0, stream>>>(fA, sc_e1, sh_e1, BB * NN * 64, 64);
  k_emb2<<<(BB * NN * 64 + thr - 1) / thr, thr, 0, stream>>>(fA, emb_w2, fB);
  k_stats_direct<64><<<64, 256, 0, stream>>>(fB, BB * NN, emb_g2, emb_b2, sc_e2, sh_e2);
  k_normrelu<<<(BB * NN * 64 + thr - 1) / thr, thr, 0, stream>>>(fB, sc_e2, sh_e2, BB * NN * 64, 64);

  k_f2bf<<<(128 * 128 + 255) / 256, 256, 0, stream>>>(sg1_w1, wb11, 128 * 128);
  k_f2bf<<<(128 * 128 + 255) / 256, 256, 0, stream>>>(sg1_w2, wb12, 128 * 128);
  k_f2bf<<<(512 * 256 + 255) / 256, 256, 0, stream>>>(sg2_w1, wb21, 512 * 256);
  k_f2bf<<<(512 * 512 + 255) / 256, 256, 0, stream>>>(sg2_w2, wb22, 512 * 512);

  k_fps<<<BB, 256, 0, stream>>>(xyz, NN, SS1, fps1, nx1);
  k_knn<<<BB * SS1, 256, 0, stream>>>(xyz, nx1, NN, SS1, knn1);

  // ---- SG1: M=262144, K=128, N=128
  k_gather<64><<<BB * SS1, 256, 0, stream>>>(fB, NN, fps1, knn1, SS1, Abuf);
  k_mgemm<128, 0><<<2048, 256, 0, stream>>>(Abuf, wb11, 128, 2048, sg1_cb1, Hbuf,
                                            nullptr, nullptr, nullptr, nullptr);
  k_colstats<<<1024, 256, 0, stream>>>(Hbuf, 128, 16, rsA, rqA);
  k_finalize<<<1, 128, 0, stream>>>(rsA, rqA, 128, 262144, sg1_g1, sg1_b1, sc11, sh11);
  k_bnrelu<<<1024, 256, 0, stream>>>(Hbuf, 128, 16, sc11, sh11);
  k_mgemm<128, 1><<<2048, 256, 0, stream>>>(Hbuf, wb12, 128, 2048, sg1_cb2, nullptr,
                                            maxb, minb, rsB, rqB);
  k_finalize<<<1, 128, 0, stream>>>(rsB, rqB, 128, 262144, sg1_g2, sg1_b2, sc12, sh12);
  k_final_feat<<<(BB * SS1 * 128 + thr - 1) / thr, thr, 0, stream>>>(maxb, minb, sc12, sh12,
                                                                     f1, BB * SS1 * 128, 128);

  k_fps<<<BB, 256, 0, stream>>>(nx1, SS1, SS2, fps2, nx2);
  k_knn<<<BB * SS2, 256, 0, stream>>>(nx1, nx2, SS1, SS2, knn2);

  // ---- SG2: M=131072, K=256->512, N=512
  k_gather<128><<<BB * SS2, 256, 0, stream>>>(f1, SS1, fps2, knn2, SS2, Abuf);
  k_mgemm<256, 0><<<1024 * 4, 256, 0, stream>>>(Abuf, wb21, 512, 1024, sg2_cb1, Hbuf,
                                                nullptr, nullptr, nullptr, nullptr);
  k_colstats<<<2048, 256, 0, stream>>>(Hbuf, 512, 16, rsC, rqC);
  k_finalize<<<4, 128, 0, stream>>>(rsC, rqC, 512, 131072, sg2_g1, sg2_b1, sc21, sh21);
  k_bnrelu<<<2048, 256, 0, stream>>>(Hbuf, 512, 16, sc21, sh21);
  k_mgemm<512, 1><<<1024 * 4, 256, 0, stream>>>(Hbuf, wb22, 512, 1024, sg2_cb2, nullptr,
                                                maxb, minb, rsD, rqD);
  k_finalize<<<4, 128, 0, stream>>>(rsD, rqD, 512, 131072, sg2_g2, sg2_b2, sc22, sh22);
  k_final_out<<<(BB * SS2 * 512 + thr - 1) / thr, thr, 0, stream>>>(maxb, minb, sc22, sh22,
                                                                    (float*)d_out);
}

// Round 3
// 1995.992 us; speedup vs baseline: 2.4659x; 1.1669x over previous
//
#include <hip/hip_runtime.h>
#include <hip/hip_bf16.h>

#define EPS_BN 1e-5f
constexpr int BB = 16, NN = 2048, SS1 = 512, SS2 = 256, KNb = 32;

typedef short bf16x8 __attribute__((ext_vector_type(8)));
typedef float f32x4 __attribute__((ext_vector_type(4)));

__device__ inline float bflo(unsigned u) { return __uint_as_float(u << 16); }
__device__ inline float bfhi(unsigned u) { return __uint_as_float(u & 0xffff0000u); }
__device__ inline unsigned short f2bf_bits(float v) {
  __hip_bfloat16 h = __float2bfloat16(v);
  return *reinterpret_cast<unsigned short*>(&h);
}

// ---------------------------------------------------------------- transpose
__global__ void k_transpose(const float* __restrict__ x, float* __restrict__ xyz) {
  int idx = blockIdx.x * blockDim.x + threadIdx.x;
  if (idx >= BB * NN * 3) return;
  int c = idx % 3; int n = (idx / 3) % NN; int b = idx / (3 * NN);
  xyz[idx] = x[((size_t)b * 3 + c) * NN + n];
}

// ---------------------------------------------------------------- embedding (cheap, keep scalar)
__global__ void k_emb1(const float* __restrict__ xyz, const float* __restrict__ w,
                       float* __restrict__ out) {
  int idx = blockIdx.x * blockDim.x + threadIdx.x;
  if (idx >= BB * NN * 64) return;
  int o = idx & 63; int pt = idx >> 6;
  const float* p = xyz + (size_t)pt * 3;
  const float* wr = w + o * 3;
  out[idx] = p[0] * wr[0] + p[1] * wr[1] + p[2] * wr[2];
}

__global__ void k_emb2(const float* __restrict__ fin, const float* __restrict__ w,
                       float* __restrict__ out) {
  int idx = blockIdx.x * blockDim.x + threadIdx.x;
  if (idx >= BB * NN * 64) return;
  int o = idx & 63; int pt = idx >> 6;
  const float* f = fin + (size_t)pt * 64;
  const float* wr = w + o * 64;
  float acc = 0.f;
#pragma unroll
  for (int c = 0; c < 64; c++) acc += f[c] * wr[c];
  out[idx] = acc;
}

template <int O>
__global__ void k_stats_direct(const float* __restrict__ data, int rows,
                               const float* __restrict__ gamma, const float* __restrict__ beta,
                               float* __restrict__ scale, float* __restrict__ shift) {
  int o = blockIdx.x; int t = threadIdx.x;
  double s = 0.0, s2 = 0.0;
  for (int r = t; r < rows; r += 256) {
    float v = data[(size_t)r * O + o];
    s += v; s2 += (double)v * (double)v;
  }
  __shared__ double ls[256], ls2[256];
  ls[t] = s; ls2[t] = s2; __syncthreads();
  for (int off = 128; off > 0; off >>= 1) {
    if (t < off) { ls[t] += ls[t + off]; ls2[t] += ls2[t + off]; }
    __syncthreads();
  }
  if (t == 0) {
    double mean = ls[0] / rows;
    double var = ls2[0] / rows - mean * mean;
    float sc = gamma[o] * rsqrtf((float)var + EPS_BN);
    scale[o] = sc; shift[o] = beta[o] - (float)mean * sc;
  }
}

__global__ void k_normrelu(float* __restrict__ data, const float* __restrict__ scale,
                           const float* __restrict__ shift, int total, int O) {
  int idx = blockIdx.x * blockDim.x + threadIdx.x;
  if (idx >= total) return;
  int o = idx % O;
  data[idx] = fmaxf(data[idx] * scale[o] + shift[o], 0.f);
}

// ---------------------------------------------------------------- FPS: ONE WAVE per batch.
// Points + running min-distance live in registers (N/64 per lane); LDS mirror only
// for the uniform broadcast of the current farthest point. No barriers in the loop.
template <int N>
__global__ __launch_bounds__(64) void k_fps_wave(const float* __restrict__ xyz, int S,
                                                 int* __restrict__ fpsidx,
                                                 float* __restrict__ newxyz) {
  constexpr int PPL = N / 64;
  int b = blockIdx.x; int lane = threadIdx.x;
  __shared__ float sx[N], sy[N], sz[N];
  float px[PPL], py[PPL], pz[PPL], ds[PPL];
#pragma unroll
  for (int r = 0; r < PPL; r++) {
    int i = r * 64 + lane;
    size_t base = ((size_t)b * N + i) * 3;
    float xx = xyz[base], yy = xyz[base + 1], zz = xyz[base + 2];
    px[r] = xx; py[r] = yy; pz[r] = zz;
    sx[i] = xx; sy[i] = yy; sz[i] = zz;
    ds[r] = 1e10f;
  }
  __syncthreads();
  int far = 0;
  for (int it = 0; it < S; it++) {
    float fx = sx[far], fy = sy[far], fz = sz[far];  // uniform addr -> LDS broadcast
    if (lane == 0) {
      fpsidx[b * S + it] = far;
      size_t ob = ((size_t)b * S + it) * 3;
      newxyz[ob] = fx; newxyz[ob + 1] = fy; newxyz[ob + 2] = fz;
    }
    float bv = -1.f; int bi = 0;
#pragma unroll
    for (int r = 0; r < PPL; r++) {
      float dx = px[r] - fx, dy = py[r] - fy, dz = pz[r] - fz;
      float d = dx * dx + dy * dy + dz * dz;
      float od = ds[r];
      float nd = d < od ? d : od;
      ds[r] = nd;
      if (nd > bv) { bv = nd; bi = r * 64 + lane; }  // ascending idx per lane: keeps lowest on tie
    }
#pragma unroll
    for (int off = 32; off > 0; off >>= 1) {
      float ov = __shfl_down(bv, off); int oi = __shfl_down(bi, off);
      if (ov > bv || (ov == bv && oi < bi)) { bv = ov; bi = oi; }
    }
    far = __shfl(bi, 0);
  }
}

// ---------------------------------------------------------------- KNN (one block per center)
__global__ void k_knn(const float* __restrict__ pts, const float* __restrict__ ctr,
                      int N, int S, int* __restrict__ knn) {
  int blk = blockIdx.x; int b = blk / S; int t = threadIdx.x;
  __shared__ float d2[2048];
  __shared__ float rv[4]; __shared__ int ri[4];
  size_t cb = ((size_t)blk) * 3;
  float cx = ctr[cb], cy = ctr[cb + 1], cz = ctr[cb + 2];
  float cn = cx * cx + cy * cy + cz * cz;
  for (int i = t; i < N; i += 256) {
    size_t pb = ((size_t)b * N + i) * 3;
    float xx = pts[pb], yy = pts[pb + 1], zz = pts[pb + 2];
    d2[i] = cn - 2.f * (cx * xx + cy * yy + cz * zz) + (xx * xx + yy * yy + zz * zz);
  }
  __syncthreads();
  for (int kk = 0; kk < KNb; kk++) {
    float bv = 3.4e38f; int bi = 0;
    for (int i = t; i < N; i += 256) {
      float v = d2[i];
      if (v < bv) { bv = v; bi = i; }
    }
#pragma unroll
    for (int off = 32; off > 0; off >>= 1) {
      float ov = __shfl_down(bv, off); int oi = __shfl_down(bi, off);
      if (ov < bv || (ov == bv && oi < bi)) { bv = ov; bi = oi; }
    }
    int wid = t >> 6, lane = t & 63;
    if (lane == 0) { rv[wid] = bv; ri[wid] = bi; }
    __syncthreads();
    if (t == 0) {
      float bbv = rv[0]; int bbi = ri[0];
      for (int w = 1; w < 4; w++) {
        if (rv[w] < bbv || (rv[w] == bbv && ri[w] < bbi)) { bbv = rv[w]; bbi = ri[w]; }
      }
      knn[(size_t)blk * KNb + kk] = bbi;
      d2[bbi] = 3.4e38f;
    }
    __syncthreads();
  }
}

// ---------------------------------------------------------------- fp32 -> bf16 convert
__global__ void k_f2bf(const float* __restrict__ w, __hip_bfloat16* __restrict__ o, int n) {
  int i = blockIdx.x * blockDim.x + threadIdx.x;
  if (i < n) o[i] = __float2bfloat16(w[i]);
}

// ---------------------------------------------------------------- gather: A = [rel | cf] bf16
template <int D>
__global__ __launch_bounds__(256) void k_gather(const float* __restrict__ feat, int N,
                                                const int* __restrict__ fpsidx,
                                                const int* __restrict__ knn, int S,
                                                __hip_bfloat16* __restrict__ A) {
  int blk = blockIdx.x; int b = blk / S; int t = threadIdx.x;
  __shared__ float cf[D]; __shared__ int nbr[KNb];
  if (t < KNb) nbr[t] = knn[(size_t)blk * KNb + t];
  int center = fpsidx[blk];
  for (int c = t; c < D; c += 256) cf[c] = feat[((size_t)b * N + center) * D + c];
  __syncthreads();
  for (int i = t; i < KNb * D; i += 256) {
    int kk = i / D, c = i - kk * D;
    float v = feat[((size_t)b * N + nbr[kk]) * D + c];
    size_t row = (size_t)blk * KNb + kk;
    A[row * (2 * D) + c] = __float2bfloat16(v - cf[c]);
    A[row * (2 * D) + D + c] = __float2bfloat16(cf[c]);
  }
}

// ---------------------------------------------------------------- MFMA GEMM: C = A[M,K] @ W[N,K]^T + bias
// EPI 0: store bf16 C. EPI 1: per-32-row-group max/min + column sum/sumsq (C not materialized).
template <int K, int EPI>
__global__ __launch_bounds__(256) void k_mgemm(
    const __hip_bfloat16* __restrict__ A, const __hip_bfloat16* __restrict__ W,
    int N, int Mtiles, const float* __restrict__ bias,
    __hip_bfloat16* __restrict__ Hout,
    float* __restrict__ maxb, float* __restrict__ minb,
    double* __restrict__ rsum, double* __restrict__ rsq) {
  constexpr int SP = 40;  // LDS row stride in shorts (padded: 80B = 20 banks -> 2-way max)
  int bm = blockIdx.x % Mtiles; int bn = blockIdx.x / Mtiles;
  int t = threadIdx.x; int w = t >> 6; int lane = t & 63;
  int wm = w & 1, wn = w >> 1; int quad = lane >> 4; int l15 = lane & 15;
  __shared__ short As[128 * SP];
  __shared__ short Ws[128 * SP];
  f32x4 acc[4][4];
  f32x4 zero = {0.f, 0.f, 0.f, 0.f};
#pragma unroll
  for (int i = 0; i < 4; i++)
#pragma unroll
    for (int j = 0; j < 4; j++) acc[i][j] = zero;

  int srow = t >> 2, sseg = t & 3;
  const short* Ag = (const short*)A;
  const short* Wg = (const short*)W;
  size_t arow0 = (size_t)bm * 128;
  size_t wrow0 = (size_t)bn * 128;

  for (int k0 = 0; k0 < K; k0 += 32) {
    __syncthreads();
    uint4 a0 = *(const uint4*)(Ag + (arow0 + srow) * K + k0 + sseg * 8);
    uint4 a1 = *(const uint4*)(Ag + (arow0 + srow + 64) * K + k0 + sseg * 8);
    uint4 b0 = *(const uint4*)(Wg + (wrow0 + srow) * K + k0 + sseg * 8);
    uint4 b1 = *(const uint4*)(Wg + (wrow0 + srow + 64) * K + k0 + sseg * 8);
    *(uint4*)(As + srow * SP + sseg * 8) = a0;
    *(uint4*)(As + (srow + 64) * SP + sseg * 8) = a1;
    *(uint4*)(Ws + srow * SP + sseg * 8) = b0;
    *(uint4*)(Ws + (srow + 64) * SP + sseg * 8) = b1;
    __syncthreads();
    bf16x8 af[4], bfr[4];
#pragma unroll
    for (int i = 0; i < 4; i++)
      af[i] = *(const bf16x8*)(As + (wm * 64 + i * 16 + l15) * SP + quad * 8);
#pragma unroll
    for (int j = 0; j < 4; j++)
      bfr[j] = *(const bf16x8*)(Ws + (wn * 64 + j * 16 + l15) * SP + quad * 8);
#pragma unroll
    for (int i = 0; i < 4; i++)
#pragma unroll
      for (int j = 0; j < 4; j++)
        acc[i][j] = __builtin_amdgcn_mfma_f32_16x16x32_bf16(af[i], bfr[j], acc[i][j], 0, 0, 0);
  }

  if constexpr (EPI == 0) {
#pragma unroll
    for (int i = 0; i < 4; i++)
#pragma unroll
      for (int j = 0; j < 4; j++) {
        int col = bn * 128 + wn * 64 + j * 16 + l15;
        float bs = bias[col];
#pragma unroll
        for (int r = 0; r < 4; r++) {
          int row = bm * 128 + wm * 64 + i * 16 + quad * 4 + r;
          Hout[(size_t)row * N + col] = __float2bfloat16(acc[i][j][r] + bs);
        }
      }
  } else {
    __shared__ float buf[128][33];
    for (int s = 0; s < 4; s++) {
      __syncthreads();
      if (wn == (s >> 1)) {
        int jb = 2 * (s & 1);
#pragma unroll
        for (int jj = 0; jj < 2; jj++) {
          int j = jb + jj;
          int lcol = jj * 16 + l15;
          float bs = bias[bn * 128 + s * 32 + lcol];
#pragma unroll
          for (int i = 0; i < 4; i++)
#pragma unroll
            for (int r = 0; r < 4; r++)
              buf[wm * 64 + i * 16 + quad * 4 + r][lcol] = acc[i][j][r] + bs;
        }
      }
      __syncthreads();
      if (t < 128) {
        int g = t >> 5, c = t & 31;
        float mx = -3.4e38f, mn = 3.4e38f, su = 0.f, sq = 0.f;
#pragma unroll
        for (int r = 0; r < 32; r++) {
          float v = buf[g * 32 + r][c];
          mx = fmaxf(mx, v); mn = fminf(mn, v);
          su += v; sq += v * v;
        }
        int col = bn * 128 + s * 32 + c;
        size_t gidx = (size_t)bm * 4 + g;
        maxb[gidx * N + col] = mx;
        minb[gidx * N + col] = mn;
        int rep = blockIdx.x & 63;
        atomicAdd(&rsum[(size_t)rep * N + col], (double)su);
        atomicAdd(&rsq[(size_t)rep * N + col], (double)sq);
      }
    }
  }
}

// ---------------------------------------------------------------- column stats over bf16 matrix
__global__ __launch_bounds__(256) void k_colstats(const __hip_bfloat16* __restrict__ Hm, int O,
                                                  int iters, double* __restrict__ rsum,
                                                  double* __restrict__ rsq) {
  __shared__ float lsum[512], lsq[512];
  int t = threadIdx.x;
  for (int c = t; c < O; c += 256) { lsum[c] = 0.f; lsq[c] = 0.f; }
  __syncthreads();
  size_t base = (size_t)blockIdx.x * 2048 * iters + t * 8;
  float as[8], aq[8];
#pragma unroll
  for (int j = 0; j < 8; j++) { as[j] = 0.f; aq[j] = 0.f; }
  const unsigned* Hu = (const unsigned*)Hm;
  for (int it = 0; it < iters; it++) {
    uint4 raw = *(const uint4*)(Hu + (base + (size_t)it * 2048) / 2);
    unsigned ws_[4] = {raw.x, raw.y, raw.z, raw.w};
#pragma unroll
    for (int k = 0; k < 4; k++) {
      float v0 = bflo(ws_[k]), v1 = bfhi(ws_[k]);
      as[2 * k] += v0; aq[2 * k] += v0 * v0;
      as[2 * k + 1] += v1; aq[2 * k + 1] += v1 * v1;
    }
  }
  int c0 = (t * 8) & (O - 1);
#pragma unroll
  for (int j = 0; j < 8; j++) {
    atomicAdd(&lsum[c0 + j], as[j]);
    atomicAdd(&lsq[c0 + j], aq[j]);
  }
  __syncthreads();
  int rep = blockIdx.x & 63;
  for (int c = t; c < O; c += 256) {
    atomicAdd(&rsum[(size_t)rep * O + c], (double)lsum[c]);
    atomicAdd(&rsq[(size_t)rep * O + c], (double)lsq[c]);
  }
}

// ---------------------------------------------------------------- in-place BN+ReLU on bf16 matrix
__global__ __launch_bounds__(256) void k_bnrelu(__hip_bfloat16* __restrict__ Hm, int O, int iters,
                                                const float* __restrict__ sc,
                                                const float* __restrict__ sh) {
  int t = threadIdx.x;
  size_t base = (size_t)blockIdx.x * 2048 * iters + t * 8;
  int c0 = (t * 8) & (O - 1);
  float s[8], h[8];
#pragma unroll
  for (int j = 0; j < 8; j++) { s[j] = sc[c0 + j]; h[j] = sh[c0 + j]; }
  unsigned* Hu = (unsigned*)Hm;
  for (int it = 0; it < iters; it++) {
    size_t e = (base + (size_t)it * 2048) / 2;
    uint4 raw = *(uint4*)(Hu + e);
    unsigned ws_[4] = {raw.x, raw.y, raw.z, raw.w};
    unsigned out[4];
#pragma unroll
    for (int k = 0; k < 4; k++) {
      float v0 = fmaxf(bflo(ws_[k]) * s[2 * k] + h[2 * k], 0.f);
      float v1 = fmaxf(bfhi(ws_[k]) * s[2 * k + 1] + h[2 * k + 1], 0.f);
      out[k] = (unsigned)f2bf_bits(v0) | ((unsigned)f2bf_bits(v1) << 16);
    }
    uint4 o4 = {out[0], out[1], out[2], out[3]};
    *(uint4*)(Hu + e) = o4;
  }
}

// ---------------------------------------------------------------- finalize BN stats
__global__ void k_finalize(const double* __restrict__ rsum, const double* __restrict__ rsq,
                           int O, int rows,
                           const float* __restrict__ gamma, const float* __restrict__ beta,
                           float* __restrict__ scale, float* __restrict__ shift) {
  int o = blockIdx.x * blockDim.x + threadIdx.x;
  if (o >= O) return;
  double s = 0, s2 = 0;
  for (int r = 0; r < 64; r++) { s += rsum[(size_t)r * O + o]; s2 += rsq[(size_t)r * O + o]; }
  double mean = s / rows;
  double var = s2 / rows - mean * mean;
  float sc = gamma[o] * rsqrtf((float)var + EPS_BN);
  scale[o] = sc; shift[o] = beta[o] - (float)mean * sc;
}

// ---------------------------------------------------------------- epilogues
__global__ void k_final_feat(const float* __restrict__ maxb, const float* __restrict__ minb,
                             const float* __restrict__ scale, const float* __restrict__ shift,
                             float* __restrict__ out, int total, int O) {
  int idx = blockIdx.x * blockDim.x + threadIdx.x;
  if (idx >= total) return;
  int o = idx % O; float sc = scale[o];
  float sel = sc > 0.f ? maxb[idx] : minb[idx];
  out[idx] = fmaxf(sel * sc + shift[o], 0.f);
}

__global__ void k_final_out(const float* __restrict__ maxb, const float* __restrict__ minb,
                            const float* __restrict__ scale, const float* __restrict__ shift,
                            float* __restrict__ out) {
  int idx = blockIdx.x * blockDim.x + threadIdx.x;
  if (idx >= BB * SS2 * 512) return;
  int o = idx % 512; int si = (idx / 512) % SS2; int b = idx / (512 * SS2);
  float sc = scale[o];
  float sel = sc > 0.f ? maxb[idx] : minb[idx];
  out[((size_t)b * 512 + o) * SS2 + si] = fmaxf(sel * sc + shift[o], 0.f);
}

// ---------------------------------------------------------------- host
extern "C" void kernel_launch(void* const* d_in, const int* in_sizes, int n_in,
                              void* d_out, int out_size, void* d_ws, size_t ws_size,
                              hipStream_t stream) {
  const float* x       = (const float*)d_in[0];
  const float* emb_w1  = (const float*)d_in[1];
  const float* emb_g1  = (const float*)d_in[2];
  const float* emb_b1  = (const float*)d_in[3];
  const float* emb_w2  = (const float*)d_in[4];
  const float* emb_g2  = (const float*)d_in[5];
  const float* emb_b2  = (const float*)d_in[6];
  const float* sg1_w1  = (const float*)d_in[7];
  const float* sg1_cb1 = (const float*)d_in[8];
  const float* sg1_g1  = (const float*)d_in[9];
  const float* sg1_b1  = (const float*)d_in[10];
  const float* sg1_w2  = (const float*)d_in[11];
  const float* sg1_cb2 = (const float*)d_in[12];
  const float* sg1_g2  = (const float*)d_in[13];
  const float* sg1_b2  = (const float*)d_in[14];
  const float* sg2_w1  = (const float*)d_in[15];
  const float* sg2_cb1 = (const float*)d_in[16];
  const float* sg2_g1  = (const float*)d_in[17];
  const float* sg2_b1  = (const float*)d_in[18];
  const float* sg2_w2  = (const float*)d_in[19];
  const float* sg2_cb2 = (const float*)d_in[20];
  const float* sg2_g2  = (const float*)d_in[21];
  const float* sg2_b2  = (const float*)d_in[22];

  char* ws = (char*)d_ws;
  size_t off = 0;
  auto alloc = [&](size_t bytes) -> size_t {
    size_t cur = off; off += (bytes + 255) & ~(size_t)255; return cur;
  };
  float* xyz  = (float*)(ws + alloc((size_t)BB * NN * 3 * 4));
  float* fA   = (float*)(ws + alloc((size_t)BB * NN * 64 * 4));
  float* fB   = (float*)(ws + alloc((size_t)BB * NN * 64 * 4));
  float* f1   = (float*)(ws + alloc((size_t)BB * SS1 * 128 * 4));
  float* nx1  = (float*)(ws + alloc((size_t)BB * SS1 * 3 * 4));
  float* nx2  = (float*)(ws + alloc((size_t)BB * SS2 * 3 * 4));
  int* fps1   = (int*)(ws + alloc((size_t)BB * SS1 * 4));
  int* fps2   = (int*)(ws + alloc((size_t)BB * SS2 * 4));
  int* knn1   = (int*)(ws + alloc((size_t)BB * SS1 * KNb * 4));
  int* knn2   = (int*)(ws + alloc((size_t)BB * SS2 * KNb * 4));
  float* maxb = (float*)(ws + alloc((size_t)BB * SS2 * 512 * 4));
  float* minb = (float*)(ws + alloc((size_t)BB * SS2 * 512 * 4));
  float* scbuf = (float*)(ws + alloc((size_t)12 * 512 * 4));
  float* sc11 = scbuf + 4 * 512, *sh11 = scbuf + 5 * 512;
  float* sc12 = scbuf + 6 * 512, *sh12 = scbuf + 7 * 512;
  float* sc21 = scbuf + 8 * 512, *sh21 = scbuf + 9 * 512;
  float* sc22 = scbuf + 10 * 512, *sh22 = scbuf + 11 * 512;
  float* sc_e1 = scbuf + 0 * 512, *sh_e1 = scbuf + 1 * 512;
  float* sc_e2 = scbuf + 2 * 512, *sh_e2 = scbuf + 3 * 512;
  size_t statsz = (size_t)8 * 64 * 512 * 8;
  char* statz = ws + alloc(statsz);
  double* st = (double*)statz;
  double* rsA = st + 0 * 64 * 512, *rqA = st + 1 * 64 * 512;
  double* rsB = st + 2 * 64 * 512, *rqB = st + 3 * 64 * 512;
  double* rsC = st + 4 * 64 * 512, *rqC = st + 5 * 64 * 512;
  double* rsD = st + 6 * 64 * 512, *rqD = st + 7 * 64 * 512;
  // bf16 weights
  __hip_bfloat16* wb11 = (__hip_bfloat16*)(ws + alloc(128 * 128 * 2));
  __hip_bfloat16* wb12 = (__hip_bfloat16*)(ws + alloc(128 * 128 * 2));
  __hip_bfloat16* wb21 = (__hip_bfloat16*)(ws + alloc(512 * 256 * 2));
  __hip_bfloat16* wb22 = (__hip_bfloat16*)(ws + alloc(512 * 512 * 2));
  // big buffers
  __hip_bfloat16* Abuf = (__hip_bfloat16*)(ws + alloc((size_t)262144 * 128 * 2));  // 64MB
  __hip_bfloat16* Hbuf = (__hip_bfloat16*)(ws + alloc((size_t)131072 * 512 * 2));  // 128MB

  hipMemsetAsync(statz, 0, statsz, stream);

  const int thr = 256;
  k_transpose<<<(BB * NN * 3 + thr - 1) / thr, thr, 0, stream>>>(x, xyz);
  k_emb1<<<(BB * NN * 64 + thr - 1) / thr, thr, 0, stream>>>(xyz, emb_w1, fA);
  k_stats_direct<64><<<64, 256, 0, stream>>>(fA, BB * NN, emb_g1, emb_b1, sc_e1, sh_e1);
  k_normrelu<<<(BB * NN * 64 + thr - 1) / thr, thr, 0, stream>>>(fA, sc_e1, sh_e1, BB * NN * 64, 64);
  k_emb2<<<(BB * NN * 64 + thr - 1) / thr, thr, 0, stream>>>(fA, emb_w2, fB);
  k_stats_direct<64><<<64, 256, 0, stream>>>(fB, BB * NN, emb_g2, emb_b2, sc_e2, sh_e2);
  k_normrelu<<<(BB * NN * 64 + thr - 1) / thr, thr, 0, stream>>>(fB, sc_e2, sh_e2, BB * NN * 64, 64);

  k_f2bf<<<(128 * 128 + 255) / 256, 256, 0, stream>>>(sg1_w1, wb11, 128 * 128);
  k_f2bf<<<(128 * 128 + 255) / 256, 256, 0, stream>>>(sg1_w2, wb12, 128 * 128);
  k_f2bf<<<(512 * 256 + 255) / 256, 256, 0, stream>>>(sg2_w1, wb21, 512 * 256);
  k_f2bf<<<(512 * 512 + 255) / 256, 256, 0, stream>>>(sg2_w2, wb22, 512 * 512);

  k_fps_wave<NN><<<BB, 64, 0, stream>>>(xyz, SS1, fps1, nx1);
  k_knn<<<BB * SS1, 256, 0, stream>>>(xyz, nx1, NN, SS1, knn1);

  // ---- SG1: M=262144, K=128, N=128
  k_gather<64><<<BB * SS1, 256, 0, stream>>>(fB, NN, fps1, knn1, SS1, Abuf);
  k_mgemm<128, 0><<<2048, 256, 0, stream>>>(Abuf, wb11, 128, 2048, sg1_cb1, Hbuf,
                                            nullptr, nullptr, nullptr, nullptr);
  k_colstats<<<1024, 256, 0, stream>>>(Hbuf, 128, 16, rsA, rqA);
  k_finalize<<<1, 128, 0, stream>>>(rsA, rqA, 128, 262144, sg1_g1, sg1_b1, sc11, sh11);
  k_bnrelu<<<1024, 256, 0, stream>>>(Hbuf, 128, 16, sc11, sh11);
  k_mgemm<128, 1><<<2048, 256, 0, stream>>>(Hbuf, wb12, 128, 2048, sg1_cb2, nullptr,
                                            maxb, minb, rsB, rqB);
  k_finalize<<<1, 128, 0, stream>>>(rsB, rqB, 128, 262144, sg1_g2, sg1_b2, sc12, sh12);
  k_final_feat<<<(BB * SS1 * 128 + thr - 1) / thr, thr, 0, stream>>>(maxb, minb, sc12, sh12,
                                                                     f1, BB * SS1 * 128, 128);

  k_fps_wave<SS1><<<BB, 64, 0, stream>>>(nx1, SS2, fps2, nx2);
  k_knn<<<BB * SS2, 256, 0, stream>>>(nx1, nx2, SS1, SS2, knn2);

  // ---- SG2: M=131072, K=256->512, N=512
  k_gather<128><<<BB * SS2, 256, 0, stream>>>(f1, SS1, fps2, knn2, SS2, Abuf);
  k_mgemm<256, 0><<<1024 * 4, 256, 0, stream>>>(Abuf, wb21, 512, 1024, sg2_cb1, Hbuf,
                                                nullptr, nullptr, nullptr, nullptr);
  k_colstats<<<2048, 256, 0, stream>>>(Hbuf, 512, 16, rsC, rqC);
  k_finalize<<<4, 128, 0, stream>>>(rsC, rqC, 512, 131072, sg2_g1, sg2_b1, sc21, sh21);
  k_bnrelu<<<2048, 256, 0, stream>>>(Hbuf, 512, 16, sc21, sh21);
  k_mgemm<512, 1><<<1024 * 4, 256, 0, stream>>>(Hbuf, wb22, 512, 1024, sg2_cb2, nullptr,
                                                maxb, minb, rsD, rqD);
  k_finalize<<<4, 128, 0, stream>>>(rsD, rqD, 512, 131072, sg2_g2, sg2_b2, sc22, sh22);
  k_final_out<<<(BB * SS2 * 512 + thr - 1) / thr, thr, 0, stream>>>(maxb, minb, sc22, sh22,
                                                                    (float*)d_out);
}

// Round 4
// 1700.801 us; speedup vs baseline: 2.8939x; 1.1736x over previous
//
#include <hip/hip_runtime.h>
#include <hip/hip_bf16.h>

#define EPS_BN 1e-5f
constexpr int BB = 16, NN = 2048, SS1 = 512, SS2 = 256, KNb = 32;

typedef short bf16x8 __attribute__((ext_vector_type(8)));
typedef float f32x4 __attribute__((ext_vector_type(4)));

__device__ inline float bflo(unsigned u) { return __uint_as_float(u << 16); }
__device__ inline float bfhi(unsigned u) { return __uint_as_float(u & 0xffff0000u); }
__device__ inline unsigned short f2bf_bits(float v) {
  __hip_bfloat16 h = __float2bfloat16(v);
  return *reinterpret_cast<unsigned short*>(&h);
}
// monotone float->uint map (total order matches float compare, incl. negatives)
__device__ inline unsigned fmono(float v) {
  int b = __float_as_int(v);
  return (unsigned)(b ^ ((b >> 31) | 0x80000000));
}

// ---------------------------------------------------------------- transpose
__global__ void k_transpose(const float* __restrict__ x, float* __restrict__ xyz) {
  int idx = blockIdx.x * blockDim.x + threadIdx.x;
  if (idx >= BB * NN * 3) return;
  int c = idx % 3; int n = (idx / 3) % NN; int b = idx / (3 * NN);
  xyz[idx] = x[((size_t)b * 3 + c) * NN + n];
}

// ---------------------------------------------------------------- embedding (cheap, keep scalar)
__global__ void k_emb1(const float* __restrict__ xyz, const float* __restrict__ w,
                       float* __restrict__ out) {
  int idx = blockIdx.x * blockDim.x + threadIdx.x;
  if (idx >= BB * NN * 64) return;
  int o = idx & 63; int pt = idx >> 6;
  const float* p = xyz + (size_t)pt * 3;
  const float* wr = w + o * 3;
  out[idx] = p[0] * wr[0] + p[1] * wr[1] + p[2] * wr[2];
}

__global__ void k_emb2(const float* __restrict__ fin, const float* __restrict__ w,
                       float* __restrict__ out) {
  int idx = blockIdx.x * blockDim.x + threadIdx.x;
  if (idx >= BB * NN * 64) return;
  int o = idx & 63; int pt = idx >> 6;
  const float* f = fin + (size_t)pt * 64;
  const float* wr = w + o * 64;
  float acc = 0.f;
#pragma unroll
  for (int c = 0; c < 64; c++) acc += f[c] * wr[c];
  out[idx] = acc;
}

template <int O>
__global__ void k_stats_direct(const float* __restrict__ data, int rows,
                               const float* __restrict__ gamma, const float* __restrict__ beta,
                               float* __restrict__ scale, float* __restrict__ shift) {
  int o = blockIdx.x; int t = threadIdx.x;
  double s = 0.0, s2 = 0.0;
  for (int r = t; r < rows; r += 256) {
    float v = data[(size_t)r * O + o];
    s += v; s2 += (double)v * (double)v;
  }
  __shared__ double ls[256], ls2[256];
  ls[t] = s; ls2[t] = s2; __syncthreads();
  for (int off = 128; off > 0; off >>= 1) {
    if (t < off) { ls[t] += ls[t + off]; ls2[t] += ls2[t + off]; }
    __syncthreads();
  }
  if (t == 0) {
    double mean = ls[0] / rows;
    double var = ls2[0] / rows - mean * mean;
    float sc = gamma[o] * rsqrtf((float)var + EPS_BN);
    scale[o] = sc; shift[o] = beta[o] - (float)mean * sc;
  }
}

__global__ void k_normrelu(float* __restrict__ data, const float* __restrict__ scale,
                           const float* __restrict__ shift, int total, int O) {
  int idx = blockIdx.x * blockDim.x + threadIdx.x;
  if (idx >= total) return;
  int o = idx % O;
  data[idx] = fmaxf(data[idx] * scale[o] + shift[o], 0.f);
}

// ---------------------------------------------------------------- FPS: ONE WAVE per batch.
// Coords + running min-distance in REGISTERS (volatile LDS mirror only for the
// uniform far-point broadcast; volatile blocks LDS-rematerialization).
// Inner loop is max-only (4 independent accumulators, no serial argmax chain);
// index recovered by exact equality scan; single packed-u64 butterfly reduction
// (value in hi bits via monotone map, ~idx in lo => lowest-index tie-break).
template <int N>
__global__ __launch_bounds__(64, 1) void k_fps_wave(const float* __restrict__ xyz, int S,
                                                    int* __restrict__ fpsidx,
                                                    float* __restrict__ newxyz) {
  constexpr int PPL = N / 64;
  int b = blockIdx.x; int lane = threadIdx.x;
  __shared__ float sx[N], sy[N], sz[N];
  volatile float* vsx = sx; volatile float* vsy = sy; volatile float* vsz = sz;
  float px[PPL], py[PPL], pz[PPL], ds[PPL];
#pragma unroll
  for (int r = 0; r < PPL; r++) {
    int i = r * 64 + lane;
    size_t base = ((size_t)b * N + i) * 3;
    float xx = xyz[base], yy = xyz[base + 1], zz = xyz[base + 2];
    px[r] = xx; py[r] = yy; pz[r] = zz;
    vsx[i] = xx; vsy[i] = yy; vsz[i] = zz;
    ds[r] = 1e10f;
  }
  __syncthreads();
  int far = 0;
  for (int it = 0; it < S; it++) {
    float fx = sx[far], fy = sy[far], fz = sz[far];  // uniform addr -> LDS broadcast
    if (lane == 0) {
      fpsidx[b * S + it] = far;
      size_t ob = ((size_t)b * S + it) * 3;
      newxyz[ob] = fx; newxyz[ob + 1] = fy; newxyz[ob + 2] = fz;
    }
    float m0 = -1.f, m1 = -1.f, m2 = -1.f, m3 = -1.f;
#pragma unroll
    for (int r = 0; r < PPL; r += 4) {
      { float dx = px[r] - fx, dy = py[r] - fy, dz = pz[r] - fz;
        float d = dx * dx + dy * dy + dz * dz;
        float nd = d < ds[r] ? d : ds[r]; ds[r] = nd; m0 = nd > m0 ? nd : m0; }
      { float dx = px[r+1] - fx, dy = py[r+1] - fy, dz = pz[r+1] - fz;
        float d = dx * dx + dy * dy + dz * dz;
        float nd = d < ds[r+1] ? d : ds[r+1]; ds[r+1] = nd; m1 = nd > m1 ? nd : m1; }
      { float dx = px[r+2] - fx, dy = py[r+2] - fy, dz = pz[r+2] - fz;
        float d = dx * dx + dy * dy + dz * dz;
        float nd = d < ds[r+2] ? d : ds[r+2]; ds[r+2] = nd; m2 = nd > m2 ? nd : m2; }
      { float dx = px[r+3] - fx, dy = py[r+3] - fy, dz = pz[r+3] - fz;
        float d = dx * dx + dy * dy + dz * dz;
        float nd = d < ds[r+3] ? d : ds[r+3]; ds[r+3] = nd; m3 = nd > m3 ? nd : m3; }
    }
    float m = fmaxf(fmaxf(m0, m1), fmaxf(m2, m3));
    // exact lowest global index with ds == m (tree-min; idx = r*64+lane is r-major)
    int cand[PPL];
#pragma unroll
    for (int r = 0; r < PPL; r++) cand[r] = (ds[r] == m) ? (r * 64 + lane) : 0x7fffffff;
#pragma unroll
    for (int st = PPL / 2; st > 0; st >>= 1)
#pragma unroll
      for (int r = 0; r < st; r++) cand[r] = cand[r] < cand[r + st] ? cand[r] : cand[r + st];
    unsigned hi = fmono(m);
    unsigned lo = 0xFFFFFFFFu - (unsigned)cand[0];
#pragma unroll
    for (int off = 32; off > 0; off >>= 1) {
      unsigned oh = __shfl_xor(hi, off); unsigned ol = __shfl_xor(lo, off);
      bool take = (oh > hi) || (oh == hi && ol > lo);
      hi = take ? oh : hi; lo = take ? ol : lo;
    }
    far = (int)(0xFFFFFFFFu - lo);
  }
}

// ---------------------------------------------------------------- KNN: ONE WAVE per center.
// d2 in registers, no barriers; packed-u64 min-reduce (lowest-index tie-break).
template <int N, int S>
__global__ __launch_bounds__(64, 1) void k_knn_wave(const float* __restrict__ pts,
                                                    const float* __restrict__ ctr,
                                                    int* __restrict__ knn) {
  constexpr int PPL = N / 64;
  int blk = blockIdx.x; int lane = threadIdx.x;
  int b = blk / S;
  float cx = ctr[(size_t)blk * 3], cy = ctr[(size_t)blk * 3 + 1], cz = ctr[(size_t)blk * 3 + 2];
  float cn = cx * cx + cy * cy + cz * cz;
  float d2[PPL];
#pragma unroll
  for (int r = 0; r < PPL; r++) {
    int i = r * 64 + lane;
    size_t pb = ((size_t)b * N + i) * 3;
    float xx = pts[pb], yy = pts[pb + 1], zz = pts[pb + 2];
    d2[r] = cn - 2.f * (cx * xx + cy * yy + cz * zz) + (xx * xx + yy * yy + zz * zz);
  }
  for (int kk = 0; kk < KNb; kk++) {
    float a0 = d2[0], a1 = d2[1], a2 = d2[2], a3 = d2[3];
#pragma unroll
    for (int r = 4; r < PPL; r += 4) {
      a0 = fminf(a0, d2[r]); a1 = fminf(a1, d2[r + 1]);
      a2 = fminf(a2, d2[r + 2]); a3 = fminf(a3, d2[r + 3]);
    }
    float m = fminf(fminf(a0, a1), fminf(a2, a3));
    int cand[PPL];
#pragma unroll
    for (int r = 0; r < PPL; r++) cand[r] = (d2[r] == m) ? (r * 64 + lane) : 0x7fffffff;
#pragma unroll
    for (int st = PPL / 2; st > 0; st >>= 1)
#pragma unroll
      for (int r = 0; r < st; r++) cand[r] = cand[r] < cand[r + st] ? cand[r] : cand[r + st];
    unsigned hi = fmono(m);
    unsigned lo = (unsigned)cand[0];
#pragma unroll
    for (int off = 32; off > 0; off >>= 1) {
      unsigned oh = __shfl_xor(hi, off); unsigned ol = __shfl_xor(lo, off);
      bool take = (oh < hi) || (oh == hi && ol < lo);
      hi = take ? oh : hi; lo = take ? ol : lo;
    }
    int widx = (int)lo;
    if (lane == 0) knn[(size_t)blk * KNb + kk] = widx;
    int wr = widx >> 6, wl = widx & 63;
#pragma unroll
    for (int r = 0; r < PPL; r++) d2[r] = (r == wr && lane == wl) ? 3.4e38f : d2[r];
  }
}

// ---------------------------------------------------------------- fp32 -> bf16 convert
__global__ void k_f2bf(const float* __restrict__ w, __hip_bfloat16* __restrict__ o, int n) {
  int i = blockIdx.x * blockDim.x + threadIdx.x;
  if (i < n) o[i] = __float2bfloat16(w[i]);
}

// ---------------------------------------------------------------- gather: A = [rel | cf] bf16
template <int D>
__global__ __launch_bounds__(256) void k_gather(const float* __restrict__ feat, int N,
                                                const int* __restrict__ fpsidx,
                                                const int* __restrict__ knn, int S,
                                                __hip_bfloat16* __restrict__ A) {
  int blk = blockIdx.x; int b = blk / S; int t = threadIdx.x;
  __shared__ float cf[D]; __shared__ int nbr[KNb];
  if (t < KNb) nbr[t] = knn[(size_t)blk * KNb + t];
  int center = fpsidx[blk];
  for (int c = t; c < D; c += 256) cf[c] = feat[((size_t)b * N + center) * D + c];
  __syncthreads();
  for (int i = t; i < KNb * D; i += 256) {
    int kk = i / D, c = i - kk * D;
    float v = feat[((size_t)b * N + nbr[kk]) * D + c];
    size_t row = (size_t)blk * KNb + kk;
    A[row * (2 * D) + c] = __float2bfloat16(v - cf[c]);
    A[row * (2 * D) + D + c] = __float2bfloat16(cf[c]);
  }
}

// ---------------------------------------------------------------- MFMA GEMM: C = A[M,K] @ W[N,K]^T + bias
// EPI 0: store bf16 C. EPI 1: per-32-row-group max/min + column sum/sumsq (C not materialized).
template <int K, int EPI>
__global__ __launch_bounds__(256) void k_mgemm(
    const __hip_bfloat16* __restrict__ A, const __hip_bfloat16* __restrict__ W,
    int N, int Mtiles, const float* __restrict__ bias,
    __hip_bfloat16* __restrict__ Hout,
    float* __restrict__ maxb, float* __restrict__ minb,
    double* __restrict__ rsum, double* __restrict__ rsq) {
  constexpr int SP = 40;  // LDS row stride in shorts (padded: 80B = 20 banks -> 2-way max)
  int bm = blockIdx.x % Mtiles; int bn = blockIdx.x / Mtiles;
  int t = threadIdx.x; int w = t >> 6; int lane = t & 63;
  int wm = w & 1, wn = w >> 1; int quad = lane >> 4; int l15 = lane & 15;
  __shared__ short As[128 * SP];
  __shared__ short Ws[128 * SP];
  f32x4 acc[4][4];
  f32x4 zero = {0.f, 0.f, 0.f, 0.f};
#pragma unroll
  for (int i = 0; i < 4; i++)
#pragma unroll
    for (int j = 0; j < 4; j++) acc[i][j] = zero;

  int srow = t >> 2, sseg = t & 3;
  const short* Ag = (const short*)A;
  const short* Wg = (const short*)W;
  size_t arow0 = (size_t)bm * 128;
  size_t wrow0 = (size_t)bn * 128;

  for (int k0 = 0; k0 < K; k0 += 32) {
    __syncthreads();
    uint4 a0 = *(const uint4*)(Ag + (arow0 + srow) * K + k0 + sseg * 8);
    uint4 a1 = *(const uint4*)(Ag + (arow0 + srow + 64) * K + k0 + sseg * 8);
    uint4 b0 = *(const uint4*)(Wg + (wrow0 + srow) * K + k0 + sseg * 8);
    uint4 b1 = *(const uint4*)(Wg + (wrow0 + srow + 64) * K + k0 + sseg * 8);
    *(uint4*)(As + srow * SP + sseg * 8) = a0;
    *(uint4*)(As + (srow + 64) * SP + sseg * 8) = a1;
    *(uint4*)(Ws + srow * SP + sseg * 8) = b0;
    *(uint4*)(Ws + (srow + 64) * SP + sseg * 8) = b1;
    __syncthreads();
    bf16x8 af[4], bfr[4];
#pragma unroll
    for (int i = 0; i < 4; i++)
      af[i] = *(const bf16x8*)(As + (wm * 64 + i * 16 + l15) * SP + quad * 8);
#pragma unroll
    for (int j = 0; j < 4; j++)
      bfr[j] = *(const bf16x8*)(Ws + (wn * 64 + j * 16 + l15) * SP + quad * 8);
#pragma unroll
    for (int i = 0; i < 4; i++)
#pragma unroll
      for (int j = 0; j < 4; j++)
        acc[i][j] = __builtin_amdgcn_mfma_f32_16x16x32_bf16(af[i], bfr[j], acc[i][j], 0, 0, 0);
  }

  if constexpr (EPI == 0) {
#pragma unroll
    for (int i = 0; i < 4; i++)
#pragma unroll
      for (int j = 0; j < 4; j++) {
        int col = bn * 128 + wn * 64 + j * 16 + l15;
        float bs = bias[col];
#pragma unroll
        for (int r = 0; r < 4; r++) {
          int row = bm * 128 + wm * 64 + i * 16 + quad * 4 + r;
          Hout[(size_t)row * N + col] = __float2bfloat16(acc[i][j][r] + bs);
        }
      }
  } else {
    __shared__ float buf[128][33];
    for (int s = 0; s < 4; s++) {
      __syncthreads();
      if (wn == (s >> 1)) {
        int jb = 2 * (s & 1);
#pragma unroll
        for (int jj = 0; jj < 2; jj++) {
          int j = jb + jj;
          int lcol = jj * 16 + l15;
          float bs = bias[bn * 128 + s * 32 + lcol];
#pragma unroll
          for (int i = 0; i < 4; i++)
#pragma unroll
            for (int r = 0; r < 4; r++)
              buf[wm * 64 + i * 16 + quad * 4 + r][lcol] = acc[i][j][r] + bs;
        }
      }
      __syncthreads();
      if (t < 128) {
        int g = t >> 5, c = t & 31;
        float mx = -3.4e38f, mn = 3.4e38f, su = 0.f, sq = 0.f;
#pragma unroll
        for (int r = 0; r < 32; r++) {
          float v = buf[g * 32 + r][c];
          mx = fmaxf(mx, v); mn = fminf(mn, v);
          su += v; sq += v * v;
        }
        int col = bn * 128 + s * 32 + c;
        size_t gidx = (size_t)bm * 4 + g;
        maxb[gidx * N + col] = mx;
        minb[gidx * N + col] = mn;
        int rep = blockIdx.x & 63;
        atomicAdd(&rsum[(size_t)rep * N + col], (double)su);
        atomicAdd(&rsq[(size_t)rep * N + col], (double)sq);
      }
    }
  }
}

// ---------------------------------------------------------------- column stats over bf16 matrix
__global__ __launch_bounds__(256) void k_colstats(const __hip_bfloat16* __restrict__ Hm, int O,
                                                  int iters, double* __restrict__ rsum,
                                                  double* __restrict__ rsq) {
  __shared__ float lsum[512], lsq[512];
  int t = threadIdx.x;
  for (int c = t; c < O; c += 256) { lsum[c] = 0.f; lsq[c] = 0.f; }
  __syncthreads();
  size_t base = (size_t)blockIdx.x * 2048 * iters + t * 8;
  float as[8], aq[8];
#pragma unroll
  for (int j = 0; j < 8; j++) { as[j] = 0.f; aq[j] = 0.f; }
  const unsigned* Hu = (const unsigned*)Hm;
  for (int it = 0; it < iters; it++) {
    uint4 raw = *(const uint4*)(Hu + (base + (size_t)it * 2048) / 2);
    unsigned ws_[4] = {raw.x, raw.y, raw.z, raw.w};
#pragma unroll
    for (int k = 0; k < 4; k++) {
      float v0 = bflo(ws_[k]), v1 = bfhi(ws_[k]);
      as[2 * k] += v0; aq[2 * k] += v0 * v0;
      as[2 * k + 1] += v1; aq[2 * k + 1] += v1 * v1;
    }
  }
  int c0 = (t * 8) & (O - 1);
#pragma unroll
  for (int j = 0; j < 8; j++) {
    atomicAdd(&lsum[c0 + j], as[j]);
    atomicAdd(&lsq[c0 + j], aq[j]);
  }
  __syncthreads();
  int rep = blockIdx.x & 63;
  for (int c = t; c < O; c += 256) {
    atomicAdd(&rsum[(size_t)rep * O + c], (double)lsum[c]);
    atomicAdd(&rsq[(size_t)rep * O + c], (double)lsq[c]);
  }
}

// ---------------------------------------------------------------- in-place BN+ReLU on bf16 matrix
__global__ __launch_bounds__(256) void k_bnrelu(__hip_bfloat16* __restrict__ Hm, int O, int iters,
                                                const float* __restrict__ sc,
                                                const float* __restrict__ sh) {
  int t = threadIdx.x;
  size_t base = (size_t)blockIdx.x * 2048 * iters + t * 8;
  int c0 = (t * 8) & (O - 1);
  float s[8], h[8];
#pragma unroll
  for (int j = 0; j < 8; j++) { s[j] = sc[c0 + j]; h[j] = sh[c0 + j]; }
  unsigned* Hu = (unsigned*)Hm;
  for (int it = 0; it < iters; it++) {
    size_t e = (base + (size_t)it * 2048) / 2;
    uint4 raw = *(uint4*)(Hu + e);
    unsigned ws_[4] = {raw.x, raw.y, raw.z, raw.w};
    unsigned out[4];
#pragma unroll
    for (int k = 0; k < 4; k++) {
      float v0 = fmaxf(bflo(ws_[k]) * s[2 * k] + h[2 * k], 0.f);
      float v1 = fmaxf(bfhi(ws_[k]) * s[2 * k + 1] + h[2 * k + 1], 0.f);
      out[k] = (unsigned)f2bf_bits(v0) | ((unsigned)f2bf_bits(v1) << 16);
    }
    uint4 o4 = {out[0], out[1], out[2], out[3]};
    *(uint4*)(Hu + e) = o4;
  }
}

// ---------------------------------------------------------------- finalize BN stats
__global__ void k_finalize(const double* __restrict__ rsum, const double* __restrict__ rsq,
                           int O, int rows,
                           const float* __restrict__ gamma, const float* __restrict__ beta,
                           float* __restrict__ scale, float* __restrict__ shift) {
  int o = blockIdx.x * blockDim.x + threadIdx.x;
  if (o >= O) return;
  double s = 0, s2 = 0;
  for (int r = 0; r < 64; r++) { s += rsum[(size_t)r * O + o]; s2 += rsq[(size_t)r * O + o]; }
  double mean = s / rows;
  double var = s2 / rows - mean * mean;
  float sc = gamma[o] * rsqrtf((float)var + EPS_BN);
  scale[o] = sc; shift[o] = beta[o] - (float)mean * sc;
}

// ---------------------------------------------------------------- epilogues
__global__ void k_final_feat(const float* __restrict__ maxb, const float* __restrict__ minb,
                             const float* __restrict__ scale, const float* __restrict__ shift,
                             float* __restrict__ out, int total, int O) {
  int idx = blockIdx.x * blockDim.x + threadIdx.x;
  if (idx >= total) return;
  int o = idx % O; float sc = scale[o];
  float sel = sc > 0.f ? maxb[idx] : minb[idx];
  out[idx] = fmaxf(sel * sc + shift[o], 0.f);
}

__global__ void k_final_out(const float* __restrict__ maxb, const float* __restrict__ minb,
                            const float* __restrict__ scale, const float* __restrict__ shift,
                            float* __restrict__ out) {
  int idx = blockIdx.x * blockDim.x + threadIdx.x;
  if (idx >= BB * SS2 * 512) return;
  int o = idx % 512; int si = (idx / 512) % SS2; int b = idx / (512 * SS2);
  float sc = scale[o];
  float sel = sc > 0.f ? maxb[idx] : minb[idx];
  out[((size_t)b * 512 + o) * SS2 + si] = fmaxf(sel * sc + shift[o], 0.f);
}

// ---------------------------------------------------------------- host
extern "C" void kernel_launch(void* const* d_in, const int* in_sizes, int n_in,
                              void* d_out, int out_size, void* d_ws, size_t ws_size,
                              hipStream_t stream) {
  const float* x       = (const float*)d_in[0];
  const float* emb_w1  = (const float*)d_in[1];
  const float* emb_g1  = (const float*)d_in[2];
  const float* emb_b1  = (const float*)d_in[3];
  const float* emb_w2  = (const float*)d_in[4];
  const float* emb_g2  = (const float*)d_in[5];
  const float* emb_b2  = (const float*)d_in[6];
  const float* sg1_w1  = (const float*)d_in[7];
  const float* sg1_cb1 = (const float*)d_in[8];
  const float* sg1_g1  = (const float*)d_in[9];
  const float* sg1_b1  = (const float*)d_in[10];
  const float* sg1_w2  = (const float*)d_in[11];
  const float* sg1_cb2 = (const float*)d_in[12];
  const float* sg1_g2  = (const float*)d_in[13];
  const float* sg1_b2  = (const float*)d_in[14];
  const float* sg2_w1  = (const float*)d_in[15];
  const float* sg2_cb1 = (const float*)d_in[16];
  const float* sg2_g1  = (const float*)d_in[17];
  const float* sg2_b1  = (const float*)d_in[18];
  const float* sg2_w2  = (const float*)d_in[19];
  const float* sg2_cb2 = (const float*)d_in[20];
  const float* sg2_g2  = (const float*)d_in[21];
  const float* sg2_b2  = (const float*)d_in[22];

  char* ws = (char*)d_ws;
  size_t off = 0;
  auto alloc = [&](size_t bytes) -> size_t {
    size_t cur = off; off += (bytes + 255) & ~(size_t)255; return cur;
  };
  float* xyz  = (float*)(ws + alloc((size_t)BB * NN * 3 * 4));
  float* fA   = (float*)(ws + alloc((size_t)BB * NN * 64 * 4));
  float* fB   = (float*)(ws + alloc((size_t)BB * NN * 64 * 4));
  float* f1   = (float*)(ws + alloc((size_t)BB * SS1 * 128 * 4));
  float* nx1  = (float*)(ws + alloc((size_t)BB * SS1 * 3 * 4));
  float* nx2  = (float*)(ws + alloc((size_t)BB * SS2 * 3 * 4));
  int* fps1   = (int*)(ws + alloc((size_t)BB * SS1 * 4));
  int* fps2   = (int*)(ws + alloc((size_t)BB * SS2 * 4));
  int* knn1   = (int*)(ws + alloc((size_t)BB * SS1 * KNb * 4));
  int* knn2   = (int*)(ws + alloc((size_t)BB * SS2 * KNb * 4));
  float* maxb = (float*)(ws + alloc((size_t)BB * SS2 * 512 * 4));
  float* minb = (float*)(ws + alloc((size_t)BB * SS2 * 512 * 4));
  float* scbuf = (float*)(ws + alloc((size_t)12 * 512 * 4));
  float* sc11 = scbuf + 4 * 512, *sh11 = scbuf + 5 * 512;
  float* sc12 = scbuf + 6 * 512, *sh12 = scbuf + 7 * 512;
  float* sc21 = scbuf + 8 * 512, *sh21 = scbuf + 9 * 512;
  float* sc22 = scbuf + 10 * 512, *sh22 = scbuf + 11 * 512;
  float* sc_e1 = scbuf + 0 * 512, *sh_e1 = scbuf + 1 * 512;
  float* sc_e2 = scbuf + 2 * 512, *sh_e2 = scbuf + 3 * 512;
  size_t statsz = (size_t)8 * 64 * 512 * 8;
  char* statz = ws + alloc(statsz);
  double* st = (double*)statz;
  double* rsA = st + 0 * 64 * 512, *rqA = st + 1 * 64 * 512;
  double* rsB = st + 2 * 64 * 512, *rqB = st + 3 * 64 * 512;
  double* rsC = st + 4 * 64 * 512, *rqC = st + 5 * 64 * 512;
  double* rsD = st + 6 * 64 * 512, *rqD = st + 7 * 64 * 512;
  // bf16 weights
  __hip_bfloat16* wb11 = (__hip_bfloat16*)(ws + alloc(128 * 128 * 2));
  __hip_bfloat16* wb12 = (__hip_bfloat16*)(ws + alloc(128 * 128 * 2));
  __hip_bfloat16* wb21 = (__hip_bfloat16*)(ws + alloc(512 * 256 * 2));
  __hip_bfloat16* wb22 = (__hip_bfloat16*)(ws + alloc(512 * 512 * 2));
  // big buffers
  __hip_bfloat16* Abuf = (__hip_bfloat16*)(ws + alloc((size_t)262144 * 128 * 2));  // 64MB
  __hip_bfloat16* Hbuf = (__hip_bfloat16*)(ws + alloc((size_t)131072 * 512 * 2));  // 128MB

  hipMemsetAsync(statz, 0, statsz, stream);

  const int thr = 256;
  k_transpose<<<(BB * NN * 3 + thr - 1) / thr, thr, 0, stream>>>(x, xyz);
  k_emb1<<<(BB * NN * 64 + thr - 1) / thr, thr, 0, stream>>>(xyz, emb_w1, fA);
  k_stats_direct<64><<<64, 256, 0, stream>>>(fA, BB * NN, emb_g1, emb_b1, sc_e1, sh_e1);
  k_normrelu<<<(BB * NN * 64 + thr - 1) / thr, thr, 0, stream>>>(fA, sc_e1, sh_e1, BB * NN * 64, 64);
  k_emb2<<<(BB * NN * 64 + thr - 1) / thr, thr, 0, stream>>>(fA, emb_w2, fB);
  k_stats_direct<64><<<64, 256, 0, stream>>>(fB, BB * NN, emb_g2, emb_b2, sc_e2, sh_e2);
  k_normrelu<<<(BB * NN * 64 + thr - 1) / thr, thr, 0, stream>>>(fB, sc_e2, sh_e2, BB * NN * 64, 64);

  k_f2bf<<<(128 * 128 + 255) / 256, 256, 0, stream>>>(sg1_w1, wb11, 128 * 128);
  k_f2bf<<<(128 * 128 + 255) / 256, 256, 0, stream>>>(sg1_w2, wb12, 128 * 128);
  k_f2bf<<<(512 * 256 + 255) / 256, 256, 0, stream>>>(sg2_w1, wb21, 512 * 256);
  k_f2bf<<<(512 * 512 + 255) / 256, 256, 0, stream>>>(sg2_w2, wb22, 512 * 512);

  k_fps_wave<NN><<<BB, 64, 0, stream>>>(xyz, SS1, fps1, nx1);
  k_knn_wave<NN, SS1><<<BB * SS1, 64, 0, stream>>>(xyz, nx1, knn1);

  // ---- SG1: M=262144, K=128, N=128
  k_gather<64><<<BB * SS1, 256, 0, stream>>>(fB, NN, fps1, knn1, SS1, Abuf);
  k_mgemm<128, 0><<<2048, 256, 0, stream>>>(Abuf, wb11, 128, 2048, sg1_cb1, Hbuf,
                                            nullptr, nullptr, nullptr, nullptr);
  k_colstats<<<1024, 256, 0, stream>>>(Hbuf, 128, 16, rsA, rqA);
  k_finalize<<<1, 128, 0, stream>>>(rsA, rqA, 128, 262144, sg1_g1, sg1_b1, sc11, sh11);
  k_bnrelu<<<1024, 256, 0, stream>>>(Hbuf, 128, 16, sc11, sh11);
  k_mgemm<128, 1><<<2048, 256, 0, stream>>>(Hbuf, wb12, 128, 2048, sg1_cb2, nullptr,
                                            maxb, minb, rsB, rqB);
  k_finalize<<<1, 128, 0, stream>>>(rsB, rqB, 128, 262144, sg1_g2, sg1_b2, sc12, sh12);
  k_final_feat<<<(BB * SS1 * 128 + thr - 1) / thr, thr, 0, stream>>>(maxb, minb, sc12, sh12,
                                                                     f1, BB * SS1 * 128, 128);

  k_fps_wave<SS1><<<BB, 64, 0, stream>>>(nx1, SS2, fps2, nx2);
  k_knn_wave<SS1, SS2><<<BB * SS2, 64, 0, stream>>>(nx1, nx2, knn2);

  // ---- SG2: M=131072, K=256->512, N=512
  k_gather<128><<<BB * SS2, 256, 0, stream>>>(f1, SS1, fps2, knn2, SS2, Abuf);
  k_mgemm<256, 0><<<1024 * 4, 256, 0, stream>>>(Abuf, wb21, 512, 1024, sg2_cb1, Hbuf,
                                                nullptr, nullptr, nullptr, nullptr);
  k_colstats<<<2048, 256, 0, stream>>>(Hbuf, 512, 16, rsC, rqC);
  k_finalize<<<4, 128, 0, stream>>>(rsC, rqC, 512, 131072, sg2_g1, sg2_b1, sc21, sh21);
  k_bnrelu<<<2048, 256, 0, stream>>>(Hbuf, 512, 16, sc21, sh21);
  k_mgemm<512, 1><<<1024 * 4, 256, 0, stream>>>(Hbuf, wb22, 512, 1024, sg2_cb2, nullptr,
                                                maxb, minb, rsD, rqD);
  k_finalize<<<4, 128, 0, stream>>>(rsD, rqD, 512, 131072, sg2_g2, sg2_b2, sc22, sh22);
  k_final_out<<<(BB * SS2 * 512 + thr - 1) / thr, thr, 0, stream>>>(maxb, minb, sc22, sh22,
                                                                    (float*)d_out);
}

// Round 5
// 1571.801 us; speedup vs baseline: 3.1314x; 1.0821x over previous
//
#include <hip/hip_runtime.h>
#include <hip/hip_bf16.h>

#define EPS_BN 1e-5f
constexpr int BB = 16, NN = 2048, SS1 = 512, SS2 = 256, KNb = 32;

typedef short bf16x8 __attribute__((ext_vector_type(8)));
typedef float f32x4 __attribute__((ext_vector_type(4)));

__device__ inline float bflo(unsigned u) { return __uint_as_float(u << 16); }
__device__ inline float bfhi(unsigned u) { return __uint_as_float(u & 0xffff0000u); }
__device__ inline unsigned short f2bf_bits(float v) {
  __hip_bfloat16 h = __float2bfloat16(v);
  return *reinterpret_cast<unsigned short*>(&h);
}
// monotone float->uint map (total order matches float compare, incl. negatives)
__device__ inline unsigned fmono(float v) {
  int b = __float_as_int(v);
  return (unsigned)(b ^ ((b >> 31) | 0x80000000));
}

// ---- DPP compound-key wave64 reduction -------------------------------------
// One step: pull (hi,lo) from the DPP-shifted lane; invalid lanes keep self
// (old = self, bound_ctrl=false) -> idempotent combine, safe with full masks.
// After the 6-step chain lane 63 holds the wave-wide result.
template <int CTRL>
__device__ inline void dpp_step_min(unsigned& hi, unsigned& lo) {
  unsigned hs = (unsigned)__builtin_amdgcn_update_dpp((int)hi, (int)hi, CTRL, 0xF, 0xF, false);
  unsigned ls = (unsigned)__builtin_amdgcn_update_dpp((int)lo, (int)lo, CTRL, 0xF, 0xF, false);
  bool take = (hs < hi) || (hs == hi && ls < lo);
  hi = take ? hs : hi; lo = take ? ls : lo;
}
template <int CTRL>
__device__ inline void dpp_step_maxv_minidx(unsigned& hi, unsigned& lo) {
  unsigned hs = (unsigned)__builtin_amdgcn_update_dpp((int)hi, (int)hi, CTRL, 0xF, 0xF, false);
  unsigned ls = (unsigned)__builtin_amdgcn_update_dpp((int)lo, (int)lo, CTRL, 0xF, 0xF, false);
  bool take = (hs > hi) || (hs == hi && ls < lo);
  hi = take ? hs : hi; lo = take ? ls : lo;
}
__device__ inline int dpp_reduce_min_idx(unsigned hi, unsigned lo) {
  dpp_step_min<0x111>(hi, lo);  // row_shr:1
  dpp_step_min<0x112>(hi, lo);  // row_shr:2
  dpp_step_min<0x114>(hi, lo);  // row_shr:4
  dpp_step_min<0x118>(hi, lo);  // row_shr:8
  dpp_step_min<0x142>(hi, lo);  // row_bcast:15
  dpp_step_min<0x143>(hi, lo);  // row_bcast:31
  return __builtin_amdgcn_readlane((int)lo, 63);
}
__device__ inline int dpp_reduce_maxv_minidx(unsigned hi, unsigned lo) {
  dpp_step_maxv_minidx<0x111>(hi, lo);
  dpp_step_maxv_minidx<0x112>(hi, lo);
  dpp_step_maxv_minidx<0x114>(hi, lo);
  dpp_step_maxv_minidx<0x118>(hi, lo);
  dpp_step_maxv_minidx<0x142>(hi, lo);
  dpp_step_maxv_minidx<0x143>(hi, lo);
  return __builtin_amdgcn_readlane((int)lo, 63);
}

// ---------------------------------------------------------------- transpose
__global__ void k_transpose(const float* __restrict__ x, float* __restrict__ xyz) {
  int idx = blockIdx.x * blockDim.x + threadIdx.x;
  if (idx >= BB * NN * 3) return;
  int c = idx % 3; int n = (idx / 3) % NN; int b = idx / (3 * NN);
  xyz[idx] = x[((size_t)b * 3 + c) * NN + n];
}

// ---------------------------------------------------------------- embedding (cheap, keep scalar)
__global__ void k_emb1(const float* __restrict__ xyz, const float* __restrict__ w,
                       float* __restrict__ out) {
  int idx = blockIdx.x * blockDim.x + threadIdx.x;
  if (idx >= BB * NN * 64) return;
  int o = idx & 63; int pt = idx >> 6;
  const float* p = xyz + (size_t)pt * 3;
  const float* wr = w + o * 3;
  out[idx] = p[0] * wr[0] + p[1] * wr[1] + p[2] * wr[2];
}

__global__ void k_emb2(const float* __restrict__ fin, const float* __restrict__ w,
                       float* __restrict__ out) {
  int idx = blockIdx.x * blockDim.x + threadIdx.x;
  if (idx >= BB * NN * 64) return;
  int o = idx & 63; int pt = idx >> 6;
  const float* f = fin + (size_t)pt * 64;
  const float* wr = w + o * 64;
  float acc = 0.f;
#pragma unroll
  for (int c = 0; c < 64; c++) acc += f[c] * wr[c];
  out[idx] = acc;
}

template <int O>
__global__ void k_stats_direct(const float* __restrict__ data, int rows,
                               const float* __restrict__ gamma, const float* __restrict__ beta,
                               float* __restrict__ scale, float* __restrict__ shift) {
  int o = blockIdx.x; int t = threadIdx.x;
  double s = 0.0, s2 = 0.0;
  for (int r = t; r < rows; r += 256) {
    float v = data[(size_t)r * O + o];
    s += v; s2 += (double)v * (double)v;
  }
  __shared__ double ls[256], ls2[256];
  ls[t] = s; ls2[t] = s2; __syncthreads();
  for (int off = 128; off > 0; off >>= 1) {
    if (t < off) { ls[t] += ls[t + off]; ls2[t] += ls2[t + off]; }
    __syncthreads();
  }
  if (t == 0) {
    double mean = ls[0] / rows;
    double var = ls2[0] / rows - mean * mean;
    float sc = gamma[o] * rsqrtf((float)var + EPS_BN);
    scale[o] = sc; shift[o] = beta[o] - (float)mean * sc;
  }
}

__global__ void k_normrelu(float* __restrict__ data, const float* __restrict__ scale,
                           const float* __restrict__ shift, int total, int O) {
  int idx = blockIdx.x * blockDim.x + threadIdx.x;
  if (idx >= total) return;
  int o = idx % O;
  data[idx] = fmaxf(data[idx] * scale[o] + shift[o], 0.f);
}

// ---------------------------------------------------------------- FPS: ONE WAVE per batch.
// Coords + running min-distance in REGISTERS. The LDS mirror (for the uniform
// far-point broadcast) is written through an asm-laundered value so the
// compiler cannot CSE/remat the register arrays from LDS. Max-only inner loop
// (4 independent accumulators), exact equality scan for the index, DPP
// compound reduction (max value, lowest index on tie), result via readlane.
template <int N>
__global__ __launch_bounds__(64, 1) void k_fps_wave(const float* __restrict__ xyz, int S,
                                                    int* __restrict__ fpsidx,
                                                    float* __restrict__ newxyz) {
  constexpr int PPL = N / 64;
  int b = blockIdx.x; int lane = threadIdx.x;
  __shared__ float sx[N], sy[N], sz[N];
  float px[PPL], py[PPL], pz[PPL], ds[PPL];
#pragma unroll
  for (int r = 0; r < PPL; r++) {
    int i = r * 64 + lane;
    size_t base = ((size_t)b * N + i) * 3;
    float xx = xyz[base], yy = xyz[base + 1], zz = xyz[base + 2];
    px[r] = xx; py[r] = yy; pz[r] = zz;
    float ox = xx, oy = yy, oz = zz;
    asm volatile("" : "+v"(ox), "+v"(oy), "+v"(oz));  // opaque bits: kill LDS<->reg CSE
    sx[i] = ox; sy[i] = oy; sz[i] = oz;
    ds[r] = 1e10f;
  }
  __syncthreads();
  int far = 0;
  for (int it = 0; it < S; it++) {
    float fx = sx[far], fy = sy[far], fz = sz[far];  // uniform addr -> LDS broadcast
    if (lane == 0) {
      fpsidx[b * S + it] = far;
      size_t ob = ((size_t)b * S + it) * 3;
      newxyz[ob] = fx; newxyz[ob + 1] = fy; newxyz[ob + 2] = fz;
    }
    float m0 = -1.f, m1 = -1.f, m2 = -1.f, m3 = -1.f;
#pragma unroll
    for (int r = 0; r < PPL; r += 4) {
      { float dx = px[r] - fx, dy = py[r] - fy, dz = pz[r] - fz;
        float d = dx * dx + dy * dy + dz * dz;
        float nd = d < ds[r] ? d : ds[r]; ds[r] = nd; m0 = nd > m0 ? nd : m0; }
      { float dx = px[r+1] - fx, dy = py[r+1] - fy, dz = pz[r+1] - fz;
        float d = dx * dx + dy * dy + dz * dz;
        float nd = d < ds[r+1] ? d : ds[r+1]; ds[r+1] = nd; m1 = nd > m1 ? nd : m1; }
      { float dx = px[r+2] - fx, dy = py[r+2] - fy, dz = pz[r+2] - fz;
        float d = dx * dx + dy * dy + dz * dz;
        float nd = d < ds[r+2] ? d : ds[r+2]; ds[r+2] = nd; m2 = nd > m2 ? nd : m2; }
      { float dx = px[r+3] - fx, dy = py[r+3] - fy, dz = pz[r+3] - fz;
        float d = dx * dx + dy * dy + dz * dz;
        float nd = d < ds[r+3] ? d : ds[r+3]; ds[r+3] = nd; m3 = nd > m3 ? nd : m3; }
    }
    float m = fmaxf(fmaxf(m0, m1), fmaxf(m2, m3));
    // exact lowest lane-local index with ds == m (idx = r*64+lane is r-major)
    int cand[PPL];
#pragma unroll
    for (int r = 0; r < PPL; r++) cand[r] = (ds[r] == m) ? (r * 64 + lane) : 0x7fffffff;
#pragma unroll
    for (int st = PPL / 2; st > 0; st >>= 1)
#pragma unroll
      for (int r = 0; r < st; r++) cand[r] = cand[r] < cand[r + st] ? cand[r] : cand[r + st];
    far = dpp_reduce_maxv_minidx(fmono(m), (unsigned)cand[0]);
  }
}

// ---------------------------------------------------------------- KNN: ONE WAVE per center.
// d2 in registers, no barriers; DPP compound min-reduce (lowest-index tie-break).
template <int N, int S>
__global__ __launch_bounds__(64, 1) void k_knn_wave(const float* __restrict__ pts,
                                                    const float* __restrict__ ctr,
                                                    int* __restrict__ knn) {
  constexpr int PPL = N / 64;
  int blk = blockIdx.x; int lane = threadIdx.x;
  int b = blk / S;
  float cx = ctr[(size_t)blk * 3], cy = ctr[(size_t)blk * 3 + 1], cz = ctr[(size_t)blk * 3 + 2];
  float cn = cx * cx + cy * cy + cz * cz;
  float d2[PPL];
#pragma unroll
  for (int r = 0; r < PPL; r++) {
    int i = r * 64 + lane;
    size_t pb = ((size_t)b * N + i) * 3;
    float xx = pts[pb], yy = pts[pb + 1], zz = pts[pb + 2];
    d2[r] = cn - 2.f * (cx * xx + cy * yy + cz * zz) + (xx * xx + yy * yy + zz * zz);
  }
  for (int kk = 0; kk < KNb; kk++) {
    float a0 = d2[0], a1 = d2[1], a2 = d2[2], a3 = d2[3];
#pragma unroll
    for (int r = 4; r < PPL; r += 4) {
      a0 = fminf(a0, d2[r]); a1 = fminf(a1, d2[r + 1]);
      a2 = fminf(a2, d2[r + 2]); a3 = fminf(a3, d2[r + 3]);
    }
    float m = fminf(fminf(a0, a1), fminf(a2, a3));
    int cand[PPL];
#pragma unroll
    for (int r = 0; r < PPL; r++) cand[r] = (d2[r] == m) ? (r * 64 + lane) : 0x7fffffff;
#pragma unroll
    for (int st = PPL / 2; st > 0; st >>= 1)
#pragma unroll
      for (int r = 0; r < st; r++) cand[r] = cand[r] < cand[r + st] ? cand[r] : cand[r + st];
    int widx = dpp_reduce_min_idx(fmono(m), (unsigned)cand[0]);
    if (lane == 0) knn[(size_t)blk * KNb + kk] = widx;
    int wr = widx >> 6, wl = widx & 63;
#pragma unroll
    for (int r = 0; r < PPL; r++) d2[r] = (r == wr && lane == wl) ? 3.4e38f : d2[r];
  }
}

// ---------------------------------------------------------------- fp32 -> bf16 convert
__global__ void k_f2bf(const float* __restrict__ w, __hip_bfloat16* __restrict__ o, int n) {
  int i = blockIdx.x * blockDim.x + threadIdx.x;
  if (i < n) o[i] = __float2bfloat16(w[i]);
}

// ---------------------------------------------------------------- gather: A = [rel | cf] bf16
template <int D>
__global__ __launch_bounds__(256) void k_gather(const float* __restrict__ feat, int N,
                                                const int* __restrict__ fpsidx,
                                                const int* __restrict__ knn, int S,
                                                __hip_bfloat16* __restrict__ A) {
  int blk = blockIdx.x; int b = blk / S; int t = threadIdx.x;
  __shared__ float cf[D]; __shared__ int nbr[KNb];
  if (t < KNb) nbr[t] = knn[(size_t)blk * KNb + t];
  int center = fpsidx[blk];
  for (int c = t; c < D; c += 256) cf[c] = feat[((size_t)b * N + center) * D + c];
  __syncthreads();
  for (int i = t; i < KNb * D; i += 256) {
    int kk = i / D, c = i - kk * D;
    float v = feat[((size_t)b * N + nbr[kk]) * D + c];
    size_t row = (size_t)blk * KNb + kk;
    A[row * (2 * D) + c] = __float2bfloat16(v - cf[c]);
    A[row * (2 * D) + D + c] = __float2bfloat16(cf[c]);
  }
}

// ---------------------------------------------------------------- MFMA GEMM: C = A[M,K] @ W[N,K]^T + bias
// EPI 0: store bf16 C. EPI 1: per-32-row-group max/min + column sum/sumsq (C not materialized).
template <int K, int EPI>
__global__ __launch_bounds__(256) void k_mgemm(
    const __hip_bfloat16* __restrict__ A, const __hip_bfloat16* __restrict__ W,
    int N, int Mtiles, const float* __restrict__ bias,
    __hip_bfloat16* __restrict__ Hout,
    float* __restrict__ maxb, float* __restrict__ minb,
    double* __restrict__ rsum, double* __restrict__ rsq) {
  constexpr int SP = 40;  // LDS row stride in shorts (padded: 80B = 20 banks -> 2-way max)
  int bm = blockIdx.x % Mtiles; int bn = blockIdx.x / Mtiles;
  int t = threadIdx.x; int w = t >> 6; int lane = t & 63;
  int wm = w & 1, wn = w >> 1; int quad = lane >> 4; int l15 = lane & 15;
  __shared__ short As[128 * SP];
  __shared__ short Ws[128 * SP];
  f32x4 acc[4][4];
  f32x4 zero = {0.f, 0.f, 0.f, 0.f};
#pragma unroll
  for (int i = 0; i < 4; i++)
#pragma unroll
    for (int j = 0; j < 4; j++) acc[i][j] = zero;

  int srow = t >> 2, sseg = t & 3;
  const short* Ag = (const short*)A;
  const short* Wg = (const short*)W;
  size_t arow0 = (size_t)bm * 128;
  size_t wrow0 = (size_t)bn * 128;

  for (int k0 = 0; k0 < K; k0 += 32) {
    __syncthreads();
    uint4 a0 = *(const uint4*)(Ag + (arow0 + srow) * K + k0 + sseg * 8);
    uint4 a1 = *(const uint4*)(Ag + (arow0 + srow + 64) * K + k0 + sseg * 8);
    uint4 b0 = *(const uint4*)(Wg + (wrow0 + srow) * K + k0 + sseg * 8);
    uint4 b1 = *(const uint4*)(Wg + (wrow0 + srow + 64) * K + k0 + sseg * 8);
    *(uint4*)(As + srow * SP + sseg * 8) = a0;
    *(uint4*)(As + (srow + 64) * SP + sseg * 8) = a1;
    *(uint4*)(Ws + srow * SP + sseg * 8) = b0;
    *(uint4*)(Ws + (srow + 64) * SP + sseg * 8) = b1;
    __syncthreads();
    bf16x8 af[4], bfr[4];
#pragma unroll
    for (int i = 0; i < 4; i++)
      af[i] = *(const bf16x8*)(As + (wm * 64 + i * 16 + l15) * SP + quad * 8);
#pragma unroll
    for (int j = 0; j < 4; j++)
      bfr[j] = *(const bf16x8*)(Ws + (wn * 64 + j * 16 + l15) * SP + quad * 8);
#pragma unroll
    for (int i = 0; i < 4; i++)
#pragma unroll
      for (int j = 0; j < 4; j++)
        acc[i][j] = __builtin_amdgcn_mfma_f32_16x16x32_bf16(af[i], bfr[j], acc[i][j], 0, 0, 0);
  }

  if constexpr (EPI == 0) {
#pragma unroll
    for (int i = 0; i < 4; i++)
#pragma unroll
      for (int j = 0; j < 4; j++) {
        int col = bn * 128 + wn * 64 + j * 16 + l15;
        float bs = bias[col];
#pragma unroll
        for (int r = 0; r < 4; r++) {
          int row = bm * 128 + wm * 64 + i * 16 + quad * 4 + r;
          Hout[(size_t)row * N + col] = __float2bfloat16(acc[i][j][r] + bs);
        }
      }
  } else {
    __shared__ float buf[128][33];
    for (int s = 0; s < 4; s++) {
      __syncthreads();
      if (wn == (s >> 1)) {
        int jb = 2 * (s & 1);
#pragma unroll
        for (int jj = 0; jj < 2; jj++) {
          int j = jb + jj;
          int lcol = jj * 16 + l15;
          float bs = bias[bn * 128 + s * 32 + lcol];
#pragma unroll
          for (int i = 0; i < 4; i++)
#pragma unroll
            for (int r = 0; r < 4; r++)
              buf[wm * 64 + i * 16 + quad * 4 + r][lcol] = acc[i][j][r] + bs;
        }
      }
      __syncthreads();
      if (t < 128) {
        int g = t >> 5, c = t & 31;
        float mx = -3.4e38f, mn = 3.4e38f, su = 0.f, sq = 0.f;
#pragma unroll
        for (int r = 0; r < 32; r++) {
          float v = buf[g * 32 + r][c];
          mx = fmaxf(mx, v); mn = fminf(mn, v);
          su += v; sq += v * v;
        }
        int col = bn * 128 + s * 32 + c;
        size_t gidx = (size_t)bm * 4 + g;
        maxb[gidx * N + col] = mx;
        minb[gidx * N + col] = mn;
        int rep = blockIdx.x & 63;
        atomicAdd(&rsum[(size_t)rep * N + col], (double)su);
        atomicAdd(&rsq[(size_t)rep * N + col], (double)sq);
      }
    }
  }
}

// ---------------------------------------------------------------- column stats over bf16 matrix
__global__ __launch_bounds__(256) void k_colstats(const __hip_bfloat16* __restrict__ Hm, int O,
                                                  int iters, double* __restrict__ rsum,
                                                  double* __restrict__ rsq) {
  __shared__ float lsum[512], lsq[512];
  int t = threadIdx.x;
  for (int c = t; c < O; c += 256) { lsum[c] = 0.f; lsq[c] = 0.f; }
  __syncthreads();
  size_t base = (size_t)blockIdx.x * 2048 * iters + t * 8;
  float as[8], aq[8];
#pragma unroll
  for (int j = 0; j < 8; j++) { as[j] = 0.f; aq[j] = 0.f; }
  const unsigned* Hu = (const unsigned*)Hm;
  for (int it = 0; it < iters; it++) {
    uint4 raw = *(const uint4*)(Hu + (base + (size_t)it * 2048) / 2);
    unsigned ws_[4] = {raw.x, raw.y, raw.z, raw.w};
#pragma unroll
    for (int k = 0; k < 4; k++) {
      float v0 = bflo(ws_[k]), v1 = bfhi(ws_[k]);
      as[2 * k] += v0; aq[2 * k] += v0 * v0;
      as[2 * k + 1] += v1; aq[2 * k + 1] += v1 * v1;
    }
  }
  int c0 = (t * 8) & (O - 1);
#pragma unroll
  for (int j = 0; j < 8; j++) {
    atomicAdd(&lsum[c0 + j], as[j]);
    atomicAdd(&lsq[c0 + j], aq[j]);
  }
  __syncthreads();
  int rep = blockIdx.x & 63;
  for (int c = t; c < O; c += 256) {
    atomicAdd(&rsum[(size_t)rep * O + c], (double)lsum[c]);
    atomicAdd(&rsq[(size_t)rep * O + c], (double)lsq[c]);
  }
}

// ---------------------------------------------------------------- in-place BN+ReLU on bf16 matrix
__global__ __launch_bounds__(256) void k_bnrelu(__hip_bfloat16* __restrict__ Hm, int O, int iters,
                                                const float* __restrict__ sc,
                                                const float* __restrict__ sh) {
  int t = threadIdx.x;
  size_t base = (size_t)blockIdx.x * 2048 * iters + t * 8;
  int c0 = (t * 8) & (O - 1);
  float s[8], h[8];
#pragma unroll
  for (int j = 0; j < 8; j++) { s[j] = sc[c0 + j]; h[j] = sh[c0 + j]; }
  unsigned* Hu = (unsigned*)Hm;
  for (int it = 0; it < iters; it++) {
    size_t e = (base + (size_t)it * 2048) / 2;
    uint4 raw = *(uint4*)(Hu + e);
    unsigned ws_[4] = {raw.x, raw.y, raw.z, raw.w};
    unsigned out[4];
#pragma unroll
    for (int k = 0; k < 4; k++) {
      float v0 = fmaxf(bflo(ws_[k]) * s[2 * k] + h[2 * k], 0.f);
      float v1 = fmaxf(bfhi(ws_[k]) * s[2 * k + 1] + h[2 * k + 1], 0.f);
      out[k] = (unsigned)f2bf_bits(v0) | ((unsigned)f2bf_bits(v1) << 16);
    }
    uint4 o4 = {out[0], out[1], out[2], out[3]};
    *(uint4*)(Hu + e) = o4;
  }
}

// ---------------------------------------------------------------- finalize BN stats
__global__ void k_finalize(const double* __restrict__ rsum, const double* __restrict__ rsq,
                           int O, int rows,
                           const float* __restrict__ gamma, const float* __restrict__ beta,
                           float* __restrict__ scale, float* __restrict__ shift) {
  int o = blockIdx.x * blockDim.x + threadIdx.x;
  if (o >= O) return;
  double s = 0, s2 = 0;
  for (int r = 0; r < 64; r++) { s += rsum[(size_t)r * O + o]; s2 += rsq[(size_t)r * O + o]; }
  double mean = s / rows;
  double var = s2 / rows - mean * mean;
  float sc = gamma[o] * rsqrtf((float)var + EPS_BN);
  scale[o] = sc; shift[o] = beta[o] - (float)mean * sc;
}

// ---------------------------------------------------------------- epilogues
__global__ void k_final_feat(const float* __restrict__ maxb, const float* __restrict__ minb,
                             const float* __restrict__ scale, const float* __restrict__ shift,
                             float* __restrict__ out, int total, int O) {
  int idx = blockIdx.x * blockDim.x + threadIdx.x;
  if (idx >= total) return;
  int o = idx % O; float sc = scale[o];
  float sel = sc > 0.f ? maxb[idx] : minb[idx];
  out[idx] = fmaxf(sel * sc + shift[o], 0.f);
}

__global__ void k_final_out(const float* __restrict__ maxb, const float* __restrict__ minb,
                            const float* __restrict__ scale, const float* __restrict__ shift,
                            float* __restrict__ out) {
  int idx = blockIdx.x * blockDim.x + threadIdx.x;
  if (idx >= BB * SS2 * 512) return;
  int o = idx % 512; int si = (idx / 512) % SS2; int b = idx / (512 * SS2);
  float sc = scale[o];
  float sel = sc > 0.f ? maxb[idx] : minb[idx];
  out[((size_t)b * 512 + o) * SS2 + si] = fmaxf(sel * sc + shift[o], 0.f);
}

// ---------------------------------------------------------------- host
extern "C" void kernel_launch(void* const* d_in, const int* in_sizes, int n_in,
                              void* d_out, int out_size, void* d_ws, size_t ws_size,
                              hipStream_t stream) {
  const float* x       = (const float*)d_in[0];
  const float* emb_w1  = (const float*)d_in[1];
  const float* emb_g1  = (const float*)d_in[2];
  const float* emb_b1  = (const float*)d_in[3];
  const float* emb_w2  = (const float*)d_in[4];
  const float* emb_g2  = (const float*)d_in[5];
  const float* emb_b2  = (const float*)d_in[6];
  const float* sg1_w1  = (const float*)d_in[7];
  const float* sg1_cb1 = (const float*)d_in[8];
  const float* sg1_g1  = (const float*)d_in[9];
  const float* sg1_b1  = (const float*)d_in[10];
  const float* sg1_w2  = (const float*)d_in[11];
  const float* sg1_cb2 = (const float*)d_in[12];
  const float* sg1_g2  = (const float*)d_in[13];
  const float* sg1_b2  = (const float*)d_in[14];
  const float* sg2_w1  = (const float*)d_in[15];
  const float* sg2_cb1 = (const float*)d_in[16];
  const float* sg2_g1  = (const float*)d_in[17];
  const float* sg2_b1  = (const float*)d_in[18];
  const float* sg2_w2  = (const float*)d_in[19];
  const float* sg2_cb2 = (const float*)d_in[20];
  const float* sg2_g2  = (const float*)d_in[21];
  const float* sg2_b2  = (const float*)d_in[22];

  char* ws = (char*)d_ws;
  size_t off = 0;
  auto alloc = [&](size_t bytes) -> size_t {
    size_t cur = off; off += (bytes + 255) & ~(size_t)255; return cur;
  };
  float* xyz  = (float*)(ws + alloc((size_t)BB * NN * 3 * 4));
  float* fA   = (float*)(ws + alloc((size_t)BB * NN * 64 * 4));
  float* fB   = (float*)(ws + alloc((size_t)BB * NN * 64 * 4));
  float* f1   = (float*)(ws + alloc((size_t)BB * SS1 * 128 * 4));
  float* nx1  = (float*)(ws + alloc((size_t)BB * SS1 * 3 * 4));
  float* nx2  = (float*)(ws + alloc((size_t)BB * SS2 * 3 * 4));
  int* fps1   = (int*)(ws + alloc((size_t)BB * SS1 * 4));
  int* fps2   = (int*)(ws + alloc((size_t)BB * SS2 * 4));
  int* knn1   = (int*)(ws + alloc((size_t)BB * SS1 * KNb * 4));
  int* knn2   = (int*)(ws + alloc((size_t)BB * SS2 * KNb * 4));
  float* maxb = (float*)(ws + alloc((size_t)BB * SS2 * 512 * 4));
  float* minb = (float*)(ws + alloc((size_t)BB * SS2 * 512 * 4));
  float* scbuf = (float*)(ws + alloc((size_t)12 * 512 * 4));
  float* sc11 = scbuf + 4 * 512, *sh11 = scbuf + 5 * 512;
  float* sc12 = scbuf + 6 * 512, *sh12 = scbuf + 7 * 512;
  float* sc21 = scbuf + 8 * 512, *sh21 = scbuf + 9 * 512;
  float* sc22 = scbuf + 10 * 512, *sh22 = scbuf + 11 * 512;
  float* sc_e1 = scbuf + 0 * 512, *sh_e1 = scbuf + 1 * 512;
  float* sc_e2 = scbuf + 2 * 512, *sh_e2 = scbuf + 3 * 512;
  size_t statsz = (size_t)8 * 64 * 512 * 8;
  char* statz = ws + alloc(statsz);
  double* st = (double*)statz;
  double* rsA = st + 0 * 64 * 512, *rqA = st + 1 * 64 * 512;
  double* rsB = st + 2 * 64 * 512, *rqB = st + 3 * 64 * 512;
  double* rsC = st + 4 * 64 * 512, *rqC = st + 5 * 64 * 512;
  double* rsD = st + 6 * 64 * 512, *rqD = st + 7 * 64 * 512;
  // bf16 weights
  __hip_bfloat16* wb11 = (__hip_bfloat16*)(ws + alloc(128 * 128 * 2));
  __hip_bfloat16* wb12 = (__hip_bfloat16*)(ws + alloc(128 * 128 * 2));
  __hip_bfloat16* wb21 = (__hip_bfloat16*)(ws + alloc(512 * 256 * 2));
  __hip_bfloat16* wb22 = (__hip_bfloat16*)(ws + alloc(512 * 512 * 2));
  // big buffers
  __hip_bfloat16* Abuf = (__hip_bfloat16*)(ws + alloc((size_t)262144 * 128 * 2));  // 64MB
  __hip_bfloat16* Hbuf = (__hip_bfloat16*)(ws + alloc((size_t)131072 * 512 * 2));  // 128MB

  hipMemsetAsync(statz, 0, statsz, stream);

  const int thr = 256;
  k_transpose<<<(BB * NN * 3 + thr - 1) / thr, thr, 0, stream>>>(x, xyz);
  k_emb1<<<(BB * NN * 64 + thr - 1) / thr, thr, 0, stream>>>(xyz, emb_w1, fA);
  k_stats_direct<64><<<64, 256, 0, stream>>>(fA, BB * NN, emb_g1, emb_b1, sc_e1, sh_e1);
  k_normrelu<<<(BB * NN * 64 + thr - 1) / thr, thr, 0, stream>>>(fA, sc_e1, sh_e1, BB * NN * 64, 64);
  k_emb2<<<(BB * NN * 64 + thr - 1) / thr, thr, 0, stream>>>(fA, emb_w2, fB);
  k_stats_direct<64><<<64, 256, 0, stream>>>(fB, BB * NN, emb_g2, emb_b2, sc_e2, sh_e2);
  k_normrelu<<<(BB * NN * 64 + thr - 1) / thr, thr, 0, stream>>>(fB, sc_e2, sh_e2, BB * NN * 64, 64);

  k_f2bf<<<(128 * 128 + 255) / 256, 256, 0, stream>>>(sg1_w1, wb11, 128 * 128);
  k_f2bf<<<(128 * 128 + 255) / 256, 256, 0, stream>>>(sg1_w2, wb12, 128 * 128);
  k_f2bf<<<(512 * 256 + 255) / 256, 256, 0, stream>>>(sg2_w1, wb21, 512 * 256);
  k_f2bf<<<(512 * 512 + 255) / 256, 256, 0, stream>>>(sg2_w2, wb22, 512 * 512);

  k_fps_wave<NN><<<BB, 64, 0, stream>>>(xyz, SS1, fps1, nx1);
  k_knn_wave<NN, SS1><<<BB * SS1, 64, 0, stream>>>(xyz, nx1, knn1);

  // ---- SG1: M=262144, K=128, N=128
  k_gather<64><<<BB * SS1, 256, 0, stream>>>(fB, NN, fps1, knn1, SS1, Abuf);
  k_mgemm<128, 0><<<2048, 256, 0, stream>>>(Abuf, wb11, 128, 2048, sg1_cb1, Hbuf,
                                            nullptr, nullptr, nullptr, nullptr);
  k_colstats<<<1024, 256, 0, stream>>>(Hbuf, 128, 16, rsA, rqA);
  k_finalize<<<1, 128, 0, stream>>>(rsA, rqA, 128, 262144, sg1_g1, sg1_b1, sc11, sh11);
  k_bnrelu<<<1024, 256, 0, stream>>>(Hbuf, 128, 16, sc11, sh11);
  k_mgemm<128, 1><<<2048, 256, 0, stream>>>(Hbuf, wb12, 128, 2048, sg1_cb2, nullptr,
                                            maxb, minb, rsB, rqB);
  k_finalize<<<1, 128, 0, stream>>>(rsB, rqB, 128, 262144, sg1_g2, sg1_b2, sc12, sh12);
  k_final_feat<<<(BB * SS1 * 128 + thr - 1) / thr, thr, 0, stream>>>(maxb, minb, sc12, sh12,
                                                                     f1, BB * SS1 * 128, 128);

  k_fps_wave<SS1><<<BB, 64, 0, stream>>>(nx1, SS2, fps2, nx2);
  k_knn_wave<SS1, SS2><<<BB * SS2, 64, 0, stream>>>(nx1, nx2, knn2);

  // ---- SG2: M=131072, K=256->512, N=512
  k_gather<128><<<BB * SS2, 256, 0, stream>>>(f1, SS1, fps2, knn2, SS2, Abuf);
  k_mgemm<256, 0><<<1024 * 4, 256, 0, stream>>>(Abuf, wb21, 512, 1024, sg2_cb1, Hbuf,
                                                nullptr, nullptr, nullptr, nullptr);
  k_colstats<<<2048, 256, 0, stream>>>(Hbuf, 512, 16, rsC, rqC);
  k_finalize<<<4, 128, 0, stream>>>(rsC, rqC, 512, 131072, sg2_g1, sg2_b1, sc21, sh21);
  k_bnrelu<<<2048, 256, 0, stream>>>(Hbuf, 512, 16, sc21, sh21);
  k_mgemm<512, 1><<<1024 * 4, 256, 0, stream>>>(Hbuf, wb22, 512, 1024, sg2_cb2, nullptr,
                                                maxb, minb, rsD, rqD);
  k_finalize<<<4, 128, 0, stream>>>(rsD, rqD, 512, 131072, sg2_g2, sg2_b2, sc22, sh22);
  k_final_out<<<(BB * SS2 * 512 + thr - 1) / thr, thr, 0, stream>>>(maxb, minb, sc22, sh22,
                                                                    (float*)d_out);
}

// Round 7
// 1429.100 us; speedup vs baseline: 3.4441x; 1.0999x over previous
//
#include <hip/hip_runtime.h>
#include <hip/hip_bf16.h>

#define EPS_BN 1e-5f
constexpr int BB = 16, NN = 2048, SS1 = 512, SS2 = 256, KNb = 32;

typedef short bf16x8 __attribute__((ext_vector_type(8)));
typedef float f32x4 __attribute__((ext_vector_type(4)));

__device__ inline float bflo(unsigned u) { return __uint_as_float(u << 16); }
__device__ inline float bfhi(unsigned u) { return __uint_as_float(u & 0xffff0000u); }
__device__ inline unsigned short f2bf_bits(float v) {
  __hip_bfloat16 h = __float2bfloat16(v);
  return *reinterpret_cast<unsigned short*>(&h);
}
// monotone float->uint map (total order matches float compare, incl. negatives)
__device__ inline unsigned fmono(float v) {
  int b = __float_as_int(v);
  return (unsigned)(b ^ ((b >> 31) | 0x80000000));
}

// ---- DPP compound-key wave64 reduction -------------------------------------
// NOTE: results of these chains MUST be consumed unconditionally (full exec).
// Using them only inside a divergent branch lets the compiler sink the
// cross-lane ops under a partial exec mask -> garbage (round-6 lesson).
template <int CTRL>
__device__ inline void dpp_step_min(unsigned& hi, unsigned& lo) {
  unsigned hs = (unsigned)__builtin_amdgcn_update_dpp((int)hi, (int)hi, CTRL, 0xF, 0xF, false);
  unsigned ls = (unsigned)__builtin_amdgcn_update_dpp((int)lo, (int)lo, CTRL, 0xF, 0xF, false);
  bool take = (hs < hi) || (hs == hi && ls < lo);
  hi = take ? hs : hi; lo = take ? ls : lo;
}
template <int CTRL>
__device__ inline void dpp_step_maxv_minidx(unsigned& hi, unsigned& lo) {
  unsigned hs = (unsigned)__builtin_amdgcn_update_dpp((int)hi, (int)hi, CTRL, 0xF, 0xF, false);
  unsigned ls = (unsigned)__builtin_amdgcn_update_dpp((int)lo, (int)lo, CTRL, 0xF, 0xF, false);
  bool take = (hs > hi) || (hs == hi && ls < lo);
  hi = take ? hs : hi; lo = take ? ls : lo;
}
__device__ inline void dpp_chain_min(unsigned& hi, unsigned& lo) {
  dpp_step_min<0x111>(hi, lo); dpp_step_min<0x112>(hi, lo);
  dpp_step_min<0x114>(hi, lo); dpp_step_min<0x118>(hi, lo);
  dpp_step_min<0x142>(hi, lo); dpp_step_min<0x143>(hi, lo);
}
__device__ inline void dpp_chain_maxv_minidx(unsigned& hi, unsigned& lo) {
  dpp_step_maxv_minidx<0x111>(hi, lo); dpp_step_maxv_minidx<0x112>(hi, lo);
  dpp_step_maxv_minidx<0x114>(hi, lo); dpp_step_maxv_minidx<0x118>(hi, lo);
  dpp_step_maxv_minidx<0x142>(hi, lo); dpp_step_maxv_minidx<0x143>(hi, lo);
}
__device__ inline int dpp_reduce_min_idx(unsigned hi, unsigned lo) {
  dpp_chain_min(hi, lo);
  return __builtin_amdgcn_readlane((int)lo, 63);
}

// ---------------------------------------------------------------- transpose
__global__ void k_transpose(const float* __restrict__ x, float* __restrict__ xyz) {
  int idx = blockIdx.x * blockDim.x + threadIdx.x;
  if (idx >= BB * NN * 3) return;
  int c = idx % 3; int n = (idx / 3) % NN; int b = idx / (3 * NN);
  xyz[idx] = x[((size_t)b * 3 + c) * NN + n];
}

// ---------------------------------------------------------------- embedding (cheap, keep scalar)
__global__ void k_emb1(const float* __restrict__ xyz, const float* __restrict__ w,
                       float* __restrict__ out) {
  int idx = blockIdx.x * blockDim.x + threadIdx.x;
  if (idx >= BB * NN * 64) return;
  int o = idx & 63; int pt = idx >> 6;
  const float* p = xyz + (size_t)pt * 3;
  const float* wr = w + o * 3;
  out[idx] = p[0] * wr[0] + p[1] * wr[1] + p[2] * wr[2];
}

__global__ void k_emb2(const float* __restrict__ fin, const float* __restrict__ w,
                       float* __restrict__ out) {
  int idx = blockIdx.x * blockDim.x + threadIdx.x;
  if (idx >= BB * NN * 64) return;
  int o = idx & 63; int pt = idx >> 6;
  const float* f = fin + (size_t)pt * 64;
  const float* wr = w + o * 64;
  float acc = 0.f;
#pragma unroll
  for (int c = 0; c < 64; c++) acc += f[c] * wr[c];
  out[idx] = acc;
}

template <int O>
__global__ void k_stats_direct(const float* __restrict__ data, int rows,
                               const float* __restrict__ gamma, const float* __restrict__ beta,
                               float* __restrict__ scale, float* __restrict__ shift) {
  int o = blockIdx.x; int t = threadIdx.x;
  double s = 0.0, s2 = 0.0;
  for (int r = t; r < rows; r += 256) {
    float v = data[(size_t)r * O + o];
    s += v; s2 += (double)v * (double)v;
  }
  __shared__ double ls[256], ls2[256];
  ls[t] = s; ls2[t] = s2; __syncthreads();
  for (int off = 128; off > 0; off >>= 1) {
    if (t < off) { ls[t] += ls[t + off]; ls2[t] += ls2[t + off]; }
    __syncthreads();
  }
  if (t == 0) {
    double mean = ls[0] / rows;
    double var = ls2[0] / rows - mean * mean;
    float sc = gamma[o] * rsqrtf((float)var + EPS_BN);
    scale[o] = sc; shift[o] = beta[o] - (float)mean * sc;
  }
}

__global__ void k_normrelu(float* __restrict__ data, const float* __restrict__ scale,
                           const float* __restrict__ shift, int total, int O) {
  int idx = blockIdx.x * blockDim.x + threadIdx.x;
  if (idx >= total) return;
  int o = idx % O;
  data[idx] = fmaxf(data[idx] * scale[o] + shift[o], 0.f);
}

// ---------------------------------------------------------------- FPS: 4 waves (256 threads) per batch.
// Per-lane state PPL=N/256 (8 @ N=2048) -> register-resident. One barrier/iter;
// double-buffered combine slot; per-wave DPP reduce consumed UNCONDITIONALLY
// (readlane at full exec), comb written by ALL lanes (same addr, same value)
// so no cross-lane op ever sits under a divergent exec mask.
template <int N>
__global__ __launch_bounds__(256, 1) void k_fps_mw(const float* __restrict__ xyz, int S,
                                                   int* __restrict__ fpsidx,
                                                   float* __restrict__ newxyz) {
  constexpr int PPL = N / 256;
  int b = blockIdx.x; int t = threadIdx.x;
  int w = t >> 6;
  __shared__ float sx[N], sy[N], sz[N];
  __shared__ unsigned combH[2][4], combL[2][4];
  float px[PPL], py[PPL], pz[PPL], ds[PPL];
#pragma unroll
  for (int r = 0; r < PPL; r++) {
    int i = r * 256 + t;
    size_t base = ((size_t)b * N + i) * 3;
    float xx = xyz[base], yy = xyz[base + 1], zz = xyz[base + 2];
    px[r] = xx; py[r] = yy; pz[r] = zz;
    float ox = xx, oy = yy, oz = zz;
    asm volatile("" : "+v"(ox), "+v"(oy), "+v"(oz));  // opaque bits: kill LDS<->reg CSE
    sx[i] = ox; sy[i] = oy; sz[i] = oz;
    ds[r] = 1e10f;
  }
  __syncthreads();
  int far = 0; int p = 0;
  for (int it = 0; it < S; it++) {
    float fx = sx[far], fy = sy[far], fz = sz[far];  // uniform addr -> LDS broadcast
    if (t == 0) {
      fpsidx[b * S + it] = far;
      size_t ob = ((size_t)b * S + it) * 3;
      newxyz[ob] = fx; newxyz[ob + 1] = fy; newxyz[ob + 2] = fz;
    }
    float mm0 = -1.f, mm1 = -1.f, mm2 = -1.f, mm3 = -1.f;
#pragma unroll
    for (int r = 0; r < PPL; r++) {
      float dx = px[r] - fx, dy = py[r] - fy, dz = pz[r] - fz;
      float d = dx * dx + dy * dy + dz * dz;
      float nd = d < ds[r] ? d : ds[r];
      ds[r] = nd;
      if ((r & 3) == 0) mm0 = nd > mm0 ? nd : mm0;
      else if ((r & 3) == 1) mm1 = nd > mm1 ? nd : mm1;
      else if ((r & 3) == 2) mm2 = nd > mm2 ? nd : mm2;
      else mm3 = nd > mm3 ? nd : mm3;
    }
    float m = fmaxf(fmaxf(mm0, mm1), fmaxf(mm2, mm3));
    // lane-local lowest global index with ds == m (idx = r*256+t is r-major)
    int cand[PPL];
#pragma unroll
    for (int r = 0; r < PPL; r++) cand[r] = (ds[r] == m) ? (r * 256 + t) : 0x7fffffff;
#pragma unroll
    for (int st = PPL / 2; st > 0; st >>= 1)
#pragma unroll
      for (int r = 0; r < st; r++) cand[r] = cand[r] < cand[r + st] ? cand[r] : cand[r + st];
    unsigned hi = fmono(m), lo = (unsigned)cand[0];
    dpp_chain_maxv_minidx(hi, lo);
    unsigned rh = (unsigned)__builtin_amdgcn_readlane((int)hi, 63);  // full exec
    unsigned rl = (unsigned)__builtin_amdgcn_readlane((int)lo, 63);
    combH[p][w] = rh;  // all lanes of wave w: same addr, same value (benign)
    combL[p][w] = rl;
    __syncthreads();
    unsigned bh = combH[p][0], bl = combL[p][0];
#pragma unroll
    for (int ww = 1; ww < 4; ww++) {
      unsigned oh = combH[p][ww], ol = combL[p][ww];
      bool take = (oh > bh) || (oh == bh && ol < bl);
      bh = take ? oh : bh; bl = take ? ol : bl;
    }
    far = (int)bl;
    p ^= 1;
  }
}

// ---------------------------------------------------------------- KNN: ONE WAVE per center.
// d2 in registers, no barriers; DPP compound min-reduce (lowest-index tie-break).
template <int N, int S>
__global__ __launch_bounds__(64, 1) void k_knn_wave(const float* __restrict__ pts,
                                                    const float* __restrict__ ctr,
                                                    int* __restrict__ knn) {
  constexpr int PPL = N / 64;
  int blk = blockIdx.x; int lane = threadIdx.x;
  int b = blk / S;
  float cx = ctr[(size_t)blk * 3], cy = ctr[(size_t)blk * 3 + 1], cz = ctr[(size_t)blk * 3 + 2];
  float cn = cx * cx + cy * cy + cz * cz;
  float d2[PPL];
#pragma unroll
  for (int r = 0; r < PPL; r++) {
    int i = r * 64 + lane;
    size_t pb = ((size_t)b * N + i) * 3;
    float xx = pts[pb], yy = pts[pb + 1], zz = pts[pb + 2];
    d2[r] = cn - 2.f * (cx * xx + cy * yy + cz * zz) + (xx * xx + yy * yy + zz * zz);
  }
  for (int kk = 0; kk < KNb; kk++) {
    float a0 = d2[0], a1 = d2[1], a2 = d2[2], a3 = d2[3];
#pragma unroll
    for (int r = 4; r < PPL; r += 4) {
      a0 = fminf(a0, d2[r]); a1 = fminf(a1, d2[r + 1]);
      a2 = fminf(a2, d2[r + 2]); a3 = fminf(a3, d2[r + 3]);
    }
    float m = fminf(fminf(a0, a1), fminf(a2, a3));
    int cand[PPL];
#pragma unroll
    for (int r = 0; r < PPL; r++) cand[r] = (d2[r] == m) ? (r * 64 + lane) : 0x7fffffff;
#pragma unroll
    for (int st = PPL / 2; st > 0; st >>= 1)
#pragma unroll
      for (int r = 0; r < st; r++) cand[r] = cand[r] < cand[r + st] ? cand[r] : cand[r + st];
    int widx = dpp_reduce_min_idx(fmono(m), (unsigned)cand[0]);
    if (lane == 0) knn[(size_t)blk * KNb + kk] = widx;
    int wr = widx >> 6, wl = widx & 63;
#pragma unroll
    for (int r = 0; r < PPL; r++) d2[r] = (r == wr && lane == wl) ? 3.4e38f : d2[r];
  }
}

// ---------------------------------------------------------------- fp32 -> bf16 convert
__global__ void k_f2bf(const float* __restrict__ w, __hip_bfloat16* __restrict__ o, int n) {
  int i = blockIdx.x * blockDim.x + threadIdx.x;
  if (i < n) o[i] = __float2bfloat16(w[i]);
}

// ---------------------------------------------------------------- gather: A = [rel | cf] bf16
template <int D>
__global__ __launch_bounds__(256) void k_gather(const float* __restrict__ feat, int N,
                                                const int* __restrict__ fpsidx,
                                                const int* __restrict__ knn, int S,
                                                __hip_bfloat16* __restrict__ A) {
  int blk = blockIdx.x; int b = blk / S; int t = threadIdx.x;
  __shared__ float cf[D]; __shared__ int nbr[KNb];
  if (t < KNb) nbr[t] = knn[(size_t)blk * KNb + t];
  int center = fpsidx[blk];
  for (int c = t; c < D; c += 256) cf[c] = feat[((size_t)b * N + center) * D + c];
  __syncthreads();
  for (int i = t; i < KNb * D; i += 256) {
    int kk = i / D, c = i - kk * D;
    float v = feat[((size_t)b * N + nbr[kk]) * D + c];
    size_t row = (size_t)blk * KNb + kk;
    A[row * (2 * D) + c] = __float2bfloat16(v - cf[c]);
    A[row * (2 * D) + D + c] = __float2bfloat16(cf[c]);
  }
}

// ---------------------------------------------------------------- MFMA GEMM: C = A[M,K] @ W[N,K]^T + bias
// EPI 0: store bf16 C. EPI 1: per-32-row-group max/min + column sum/sumsq (C not materialized).
template <int K, int EPI>
__global__ __launch_bounds__(256) void k_mgemm(
    const __hip_bfloat16* __restrict__ A, const __hip_bfloat16* __restrict__ W,
    int N, int Mtiles, const float* __restrict__ bias,
    __hip_bfloat16* __restrict__ Hout,
    float* __restrict__ maxb, float* __restrict__ minb,
    double* __restrict__ rsum, double* __restrict__ rsq) {
  constexpr int SP = 40;  // LDS row stride in shorts (padded: 80B = 20 banks -> 2-way max)
  int bm = blockIdx.x % Mtiles; int bn = blockIdx.x / Mtiles;
  int t = threadIdx.x; int w = t >> 6; int lane = t & 63;
  int wm = w & 1, wn = w >> 1; int quad = lane >> 4; int l15 = lane & 15;
  __shared__ short As[128 * SP];
  __shared__ short Ws[128 * SP];
  f32x4 acc[4][4];
  f32x4 zero = {0.f, 0.f, 0.f, 0.f};
#pragma unroll
  for (int i = 0; i < 4; i++)
#pragma unroll
    for (int j = 0; j < 4; j++) acc[i][j] = zero;

  int srow = t >> 2, sseg = t & 3;
  const short* Ag = (const short*)A;
  const short* Wg = (const short*)W;
  size_t arow0 = (size_t)bm * 128;
  size_t wrow0 = (size_t)bn * 128;

  for (int k0 = 0; k0 < K; k0 += 32) {
    __syncthreads();
    uint4 a0 = *(const uint4*)(Ag + (arow0 + srow) * K + k0 + sseg * 8);
    uint4 a1 = *(const uint4*)(Ag + (arow0 + srow + 64) * K + k0 + sseg * 8);
    uint4 b0 = *(const uint4*)(Wg + (wrow0 + srow) * K + k0 + sseg * 8);
    uint4 b1 = *(const uint4*)(Wg + (wrow0 + srow + 64) * K + k0 + sseg * 8);
    *(uint4*)(As + srow * SP + sseg * 8) = a0;
    *(uint4*)(As + (srow + 64) * SP + sseg * 8) = a1;
    *(uint4*)(Ws + srow * SP + sseg * 8) = b0;
    *(uint4*)(Ws + (srow + 64) * SP + sseg * 8) = b1;
    __syncthreads();
    bf16x8 af[4], bfr[4];
#pragma unroll
    for (int i = 0; i < 4; i++)
      af[i] = *(const bf16x8*)(As + (wm * 64 + i * 16 + l15) * SP + quad * 8);
#pragma unroll
    for (int j = 0; j < 4; j++)
      bfr[j] = *(const bf16x8*)(Ws + (wn * 64 + j * 16 + l15) * SP + quad * 8);
#pragma unroll
    for (int i = 0; i < 4; i++)
#pragma unroll
      for (int j = 0; j < 4; j++)
        acc[i][j] = __builtin_amdgcn_mfma_f32_16x16x32_bf16(af[i], bfr[j], acc[i][j], 0, 0, 0);
  }

  if constexpr (EPI == 0) {
#pragma unroll
    for (int i = 0; i < 4; i++)
#pragma unroll
      for (int j = 0; j < 4; j++) {
        int col = bn * 128 + wn * 64 + j * 16 + l15;
        float bs = bias[col];
#pragma unroll
        for (int r = 0; r < 4; r++) {
          int row = bm * 128 + wm * 64 + i * 16 + quad * 4 + r;
          Hout[(size_t)row * N + col] = __float2bfloat16(acc[i][j][r] + bs);
        }
      }
  } else {
    __shared__ float buf[128][33];
    for (int s = 0; s < 4; s++) {
      __syncthreads();
      if (wn == (s >> 1)) {
        int jb = 2 * (s & 1);
#pragma unroll
        for (int jj = 0; jj < 2; jj++) {
          int j = jb + jj;
          int lcol = jj * 16 + l15;
          float bs = bias[bn * 128 + s * 32 + lcol];
#pragma unroll
          for (int i = 0; i < 4; i++)
#pragma unroll
            for (int r = 0; r < 4; r++)
              buf[wm * 64 + i * 16 + quad * 4 + r][lcol] = acc[i][j][r] + bs;
        }
      }
      __syncthreads();
      if (t < 128) {
        int g = t >> 5, c = t & 31;
        float mx = -3.4e38f, mn = 3.4e38f, su = 0.f, sq = 0.f;
#pragma unroll
        for (int r = 0; r < 32; r++) {
          float v = buf[g * 32 + r][c];
          mx = fmaxf(mx, v); mn = fminf(mn, v);
          su += v; sq += v * v;
        }
        int col = bn * 128 + s * 32 + c;
        size_t gidx = (size_t)bm * 4 + g;
        maxb[gidx * N + col] = mx;
        minb[gidx * N + col] = mn;
        int rep = blockIdx.x & 63;
        atomicAdd(&rsum[(size_t)rep * N + col], (double)su);
        atomicAdd(&rsq[(size_t)rep * N + col], (double)sq);
      }
    }
  }
}

// ---------------------------------------------------------------- column stats over bf16 matrix
__global__ __launch_bounds__(256) void k_colstats(const __hip_bfloat16* __restrict__ Hm, int O,
                                                  int iters, double* __restrict__ rsum,
                                                  double* __restrict__ rsq) {
  __shared__ float lsum[512], lsq[512];
  int t = threadIdx.x;
  for (int c = t; c < O; c += 256) { lsum[c] = 0.f; lsq[c] = 0.f; }
  __syncthreads();
  size_t base = (size_t)blockIdx.x * 2048 * iters + t * 8;
  float as[8], aq[8];
#pragma unroll
  for (int j = 0; j < 8; j++) { as[j] = 0.f; aq[j] = 0.f; }
  const unsigned* Hu = (const unsigned*)Hm;
  for (int it = 0; it < iters; it++) {
    uint4 raw = *(const uint4*)(Hu + (base + (size_t)it * 2048) / 2);
    unsigned ws_[4] = {raw.x, raw.y, raw.z, raw.w};
#pragma unroll
    for (int k = 0; k < 4; k++) {
      float v0 = bflo(ws_[k]), v1 = bfhi(ws_[k]);
      as[2 * k] += v0; aq[2 * k] += v0 * v0;
      as[2 * k + 1] += v1; aq[2 * k + 1] += v1 * v1;
    }
  }
  int c0 = (t * 8) & (O - 1);
#pragma unroll
  for (int j = 0; j < 8; j++) {
    atomicAdd(&lsum[c0 + j], as[j]);
    atomicAdd(&lsq[c0 + j], aq[j]);
  }
  __syncthreads();
  int rep = blockIdx.x & 63;
  for (int c = t; c < O; c += 256) {
    atomicAdd(&rsum[(size_t)rep * O + c], (double)lsum[c]);
    atomicAdd(&rsq[(size_t)rep * O + c], (double)lsq[c]);
  }
}

// ---------------------------------------------------------------- in-place BN+ReLU on bf16 matrix
__global__ __launch_bounds__(256) void k_bnrelu(__hip_bfloat16* __restrict__ Hm, int O, int iters,
                                                const float* __restrict__ sc,
                                                const float* __restrict__ sh) {
  int t = threadIdx.x;
  size_t base = (size_t)blockIdx.x * 2048 * iters + t * 8;
  int c0 = (t * 8) & (O - 1);
  float s[8], h[8];
#pragma unroll
  for (int j = 0; j < 8; j++) { s[j] = sc[c0 + j]; h[j] = sh[c0 + j]; }
  unsigned* Hu = (unsigned*)Hm;
  for (int it = 0; it < iters; it++) {
    size_t e = (base + (size_t)it * 2048) / 2;
    uint4 raw = *(uint4*)(Hu + e);
    unsigned ws_[4] = {raw.x, raw.y, raw.z, raw.w};
    unsigned out[4];
#pragma unroll
    for (int k = 0; k < 4; k++) {
      float v0 = fmaxf(bflo(ws_[k]) * s[2 * k] + h[2 * k], 0.f);
      float v1 = fmaxf(bfhi(ws_[k]) * s[2 * k + 1] + h[2 * k + 1], 0.f);
      out[k] = (unsigned)f2bf_bits(v0) | ((unsigned)f2bf_bits(v1) << 16);
    }
    uint4 o4 = {out[0], out[1], out[2], out[3]};
    *(uint4*)(Hu + e) = o4;
  }
}

// ---------------------------------------------------------------- finalize BN stats
__global__ void k_finalize(const double* __restrict__ rsum, const double* __restrict__ rsq,
                           int O, int rows,
                           const float* __restrict__ gamma, const float* __restrict__ beta,
                           float* __restrict__ scale, float* __restrict__ shift) {
  int o = blockIdx.x * blockDim.x + threadIdx.x;
  if (o >= O) return;
  double s = 0, s2 = 0;
  for (int r = 0; r < 64; r++) { s += rsum[(size_t)r * O + o]; s2 += rsq[(size_t)r * O + o]; }
  double mean = s / rows;
  double var = s2 / rows - mean * mean;
  float sc = gamma[o] * rsqrtf((float)var + EPS_BN);
  scale[o] = sc; shift[o] = beta[o] - (float)mean * sc;
}

// ---------------------------------------------------------------- epilogues
__global__ void k_final_feat(const float* __restrict__ maxb, const float* __restrict__ minb,
                             const float* __restrict__ scale, const float* __restrict__ shift,
                             float* __restrict__ out, int total, int O) {
  int idx = blockIdx.x * blockDim.x + threadIdx.x;
  if (idx >= total) return;
  int o = idx % O; float sc = scale[o];
  float sel = sc > 0.f ? maxb[idx] : minb[idx];
  out[idx] = fmaxf(sel * sc + shift[o], 0.f);
}

__global__ void k_final_out(const float* __restrict__ maxb, const float* __restrict__ minb,
                            const float* __restrict__ scale, const float* __restrict__ shift,
                            float* __restrict__ out) {
  int idx = blockIdx.x * blockDim.x + threadIdx.x;
  if (idx >= BB * SS2 * 512) return;
  int o = idx % 512; int si = (idx / 512) % SS2; int b = idx / (512 * SS2);
  float sc = scale[o];
  float sel = sc > 0.f ? maxb[idx] : minb[idx];
  out[((size_t)b * 512 + o) * SS2 + si] = fmaxf(sel * sc + shift[o], 0.f);
}

// ---------------------------------------------------------------- host
extern "C" void kernel_launch(void* const* d_in, const int* in_sizes, int n_in,
                              void* d_out, int out_size, void* d_ws, size_t ws_size,
                              hipStream_t stream) {
  const float* x       = (const float*)d_in[0];
  const float* emb_w1  = (const float*)d_in[1];
  const float* emb_g1  = (const float*)d_in[2];
  const float* emb_b1  = (const float*)d_in[3];
  const float* emb_w2  = (const float*)d_in[4];
  const float* emb_g2  = (const float*)d_in[5];
  const float* emb_b2  = (const float*)d_in[6];
  const float* sg1_w1  = (const float*)d_in[7];
  const float* sg1_cb1 = (const float*)d_in[8];
  const float* sg1_g1  = (const float*)d_in[9];
  const float* sg1_b1  = (const float*)d_in[10];
  const float* sg1_w2  = (const float*)d_in[11];
  const float* sg1_cb2 = (const float*)d_in[12];
  const float* sg1_g2  = (const float*)d_in[13];
  const float* sg1_b2  = (const float*)d_in[14];
  const float* sg2_w1  = (const float*)d_in[15];
  const float* sg2_cb1 = (const float*)d_in[16];
  const float* sg2_g1  = (const float*)d_in[17];
  const float* sg2_b1  = (const float*)d_in[18];
  const float* sg2_w2  = (const float*)d_in[19];
  const float* sg2_cb2 = (const float*)d_in[20];
  const float* sg2_g2  = (const float*)d_in[21];
  const float* sg2_b2  = (const float*)d_in[22];

  char* ws = (char*)d_ws;
  size_t off = 0;
  auto alloc = [&](size_t bytes) -> size_t {
    size_t cur = off; off += (bytes + 255) & ~(size_t)255; return cur;
  };
  float* xyz  = (float*)(ws + alloc((size_t)BB * NN * 3 * 4));
  float* fA   = (float*)(ws + alloc((size_t)BB * NN * 64 * 4));
  float* fB   = (float*)(ws + alloc((size_t)BB * NN * 64 * 4));
  float* f1   = (float*)(ws + alloc((size_t)BB * SS1 * 128 * 4));
  float* nx1  = (float*)(ws + alloc((size_t)BB * SS1 * 3 * 4));
  float* nx2  = (float*)(ws + alloc((size_t)BB * SS2 * 3 * 4));
  int* fps1   = (int*)(ws + alloc((size_t)BB * SS1 * 4));
  int* fps2   = (int*)(ws + alloc((size_t)BB * SS2 * 4));
  int* knn1   = (int*)(ws + alloc((size_t)BB * SS1 * KNb * 4));
  int* knn2   = (int*)(ws + alloc((size_t)BB * SS2 * KNb * 4));
  float* maxb = (float*)(ws + alloc((size_t)BB * SS2 * 512 * 4));
  float* minb = (float*)(ws + alloc((size_t)BB * SS2 * 512 * 4));
  float* scbuf = (float*)(ws + alloc((size_t)12 * 512 * 4));
  float* sc11 = scbuf + 4 * 512, *sh11 = scbuf + 5 * 512;
  float* sc12 = scbuf + 6 * 512, *sh12 = scbuf + 7 * 512;
  float* sc21 = scbuf + 8 * 512, *sh21 = scbuf + 9 * 512;
  float* sc22 = scbuf + 10 * 512, *sh22 = scbuf + 11 * 512;
  float* sc_e1 = scbuf + 0 * 512, *sh_e1 = scbuf + 1 * 512;
  float* sc_e2 = scbuf + 2 * 512, *sh_e2 = scbuf + 3 * 512;
  size_t statsz = (size_t)8 * 64 * 512 * 8;
  char* statz = ws + alloc(statsz);
  double* st = (double*)statz;
  double* rsA = st + 0 * 64 * 512, *rqA = st + 1 * 64 * 512;
  double* rsB = st + 2 * 64 * 512, *rqB = st + 3 * 64 * 512;
  double* rsC = st + 4 * 64 * 512, *rqC = st + 5 * 64 * 512;
  double* rsD = st + 6 * 64 * 512, *rqD = st + 7 * 64 * 512;
  // bf16 weights
  __hip_bfloat16* wb11 = (__hip_bfloat16*)(ws + alloc(128 * 128 * 2));
  __hip_bfloat16* wb12 = (__hip_bfloat16*)(ws + alloc(128 * 128 * 2));
  __hip_bfloat16* wb21 = (__hip_bfloat16*)(ws + alloc(512 * 256 * 2));
  __hip_bfloat16* wb22 = (__hip_bfloat16*)(ws + alloc(512 * 512 * 2));
  // big buffers
  __hip_bfloat16* Abuf = (__hip_bfloat16*)(ws + alloc((size_t)262144 * 128 * 2));  // 64MB
  __hip_bfloat16* Hbuf = (__hip_bfloat16*)(ws + alloc((size_t)131072 * 512 * 2));  // 128MB

  hipMemsetAsync(statz, 0, statsz, stream);

  const int thr = 256;
  k_transpose<<<(BB * NN * 3 + thr - 1) / thr, thr, 0, stream>>>(x, xyz);
  k_emb1<<<(BB * NN * 64 + thr - 1) / thr, thr, 0, stream>>>(xyz, emb_w1, fA);
  k_stats_direct<64><<<64, 256, 0, stream>>>(fA, BB * NN, emb_g1, emb_b1, sc_e1, sh_e1);
  k_normrelu<<<(BB * NN * 64 + thr - 1) / thr, thr, 0, stream>>>(fA, sc_e1, sh_e1, BB * NN * 64, 64);
  k_emb2<<<(BB * NN * 64 + thr - 1) / thr, thr, 0, stream>>>(fA, emb_w2, fB);
  k_stats_direct<64><<<64, 256, 0, stream>>>(fB, BB * NN, emb_g2, emb_b2, sc_e2, sh_e2);
  k_normrelu<<<(BB * NN * 64 + thr - 1) / thr, thr, 0, stream>>>(fB, sc_e2, sh_e2, BB * NN * 64, 64);

  k_f2bf<<<(128 * 128 + 255) / 256, 256, 0, stream>>>(sg1_w1, wb11, 128 * 128);
  k_f2bf<<<(128 * 128 + 255) / 256, 256, 0, stream>>>(sg1_w2, wb12, 128 * 128);
  k_f2bf<<<(512 * 256 + 255) / 256, 256, 0, stream>>>(sg2_w1, wb21, 512 * 256);
  k_f2bf<<<(512 * 512 + 255) / 256, 256, 0, stream>>>(sg2_w2, wb22, 512 * 512);

  k_fps_mw<NN><<<BB, 256, 0, stream>>>(xyz, SS1, fps1, nx1);
  k_knn_wave<NN, SS1><<<BB * SS1, 64, 0, stream>>>(xyz, nx1, knn1);

  // ---- SG1: M=262144, K=128, N=128
  k_gather<64><<<BB * SS1, 256, 0, stream>>>(fB, NN, fps1, knn1, SS1, Abuf);
  k_mgemm<128, 0><<<2048, 256, 0, stream>>>(Abuf, wb11, 128, 2048, sg1_cb1, Hbuf,
                                            nullptr, nullptr, nullptr, nullptr);
  k_colstats<<<1024, 256, 0, stream>>>(Hbuf, 128, 16, rsA, rqA);
  k_finalize<<<1, 128, 0, stream>>>(rsA, rqA, 128, 262144, sg1_g1, sg1_b1, sc11, sh11);
  k_bnrelu<<<1024, 256, 0, stream>>>(Hbuf, 128, 16, sc11, sh11);
  k_mgemm<128, 1><<<2048, 256, 0, stream>>>(Hbuf, wb12, 128, 2048, sg1_cb2, nullptr,
                                            maxb, minb, rsB, rqB);
  k_finalize<<<1, 128, 0, stream>>>(rsB, rqB, 128, 262144, sg1_g2, sg1_b2, sc12, sh12);
  k_final_feat<<<(BB * SS1 * 128 + thr - 1) / thr, thr, 0, stream>>>(maxb, minb, sc12, sh12,
                                                                     f1, BB * SS1 * 128, 128);

  k_fps_mw<SS1><<<BB, 256, 0, stream>>>(nx1, SS2, fps2, nx2);
  k_knn_wave<SS1, SS2><<<BB * SS2, 64, 0, stream>>>(nx1, nx2, knn2);

  // ---- SG2: M=131072, K=256->512, N=512
  k_gather<128><<<BB * SS2, 256, 0, stream>>>(f1, SS1, fps2, knn2, SS2, Abuf);
  k_mgemm<256, 0><<<1024 * 4, 256, 0, stream>>>(Abuf, wb21, 512, 1024, sg2_cb1, Hbuf,
                                                nullptr, nullptr, nullptr, nullptr);
  k_colstats<<<2048, 256, 0, stream>>>(Hbuf, 512, 16, rsC, rqC);
  k_finalize<<<4, 128, 0, stream>>>(rsC, rqC, 512, 131072, sg2_g1, sg2_b1, sc21, sh21);
  k_bnrelu<<<2048, 256, 0, stream>>>(Hbuf, 512, 16, sc21, sh21);
  k_mgemm<512, 1><<<1024 * 4, 256, 0, stream>>>(Hbuf, wb22, 512, 1024, sg2_cb2, nullptr,
                                                maxb, minb, rsD, rqD);
  k_finalize<<<4, 128, 0, stream>>>(rsD, rqD, 512, 131072, sg2_g2, sg2_b2, sc22, sh22);
  k_final_out<<<(BB * SS2 * 512 + thr - 1) / thr, thr, 0, stream>>>(maxb, minb, sc22, sh22,
                                                                    (float*)d_out);
}